// Round 15
// baseline (1906.767 us; speedup 1.0000x reference)
//
#include <hip/hip_runtime.h>
#include <hip/hip_bf16.h>

#define NN 131072      // nodes
#define NE 262144      // edges (without self loops)
#define NG 4096        // graphs
#define EMB 300
#define HS 320         // h/agg row stride (bf16, padded, cols 300..319 == 0)
#define K1 320         // GEMM1 K
#define N1 640         // padded 600 (GEMM1 out / hid stride / GEMM2 K stride)
#define K2E 608        // GEMM2 K extent (cols 600..639 of hid are exact zeros)
#define N2P 384        // padded 300 (GEMM2 B rows)
#define NLAYER 5
#define NRB (NN / 128) // 1024 row-blocks for BN partials
#define CH 2           // m-tiles chained per GEMM block

typedef __attribute__((ext_vector_type(8))) short short8;
typedef __attribute__((ext_vector_type(4))) float f32x4;
typedef __attribute__((ext_vector_type(4))) unsigned short ushort4v;

__device__ __forceinline__ void gload_lds16(const void* g, void* l) {
  __builtin_amdgcn_global_load_lds((const __attribute__((address_space(1))) void*)g,
                                   (__attribute__((address_space(3))) void*)l, 16, 0, 0);
}
__device__ __forceinline__ float b2f(unsigned short u) {
  return __uint_as_float(((unsigned)u) << 16);
}
__device__ __forceinline__ unsigned short f2b(float x) {
  __hip_bfloat16 b = __float2bfloat16(x);
  return *(unsigned short*)&b;
}

// ---------------- prep kernels ----------------

__global__ void prep_w1(const float* __restrict__ W1, __hip_bfloat16* __restrict__ W1T) {
  int idx = blockIdx.x * 256 + threadIdx.x;           // 5*640*320
  if (idx >= NLAYER * N1 * K1) return;
  int l = idx / (N1 * K1); int r = idx % (N1 * K1);
  int n = r / K1; int k = r % K1;
  float v = (n < 600 && k < 300) ? W1[(size_t)(l * 300 + k) * 600 + n] : 0.f;
  W1T[idx] = __float2bfloat16(v);
}

__global__ void prep_w2(const float* __restrict__ W2, __hip_bfloat16* __restrict__ W2T) {
  int idx = blockIdx.x * 256 + threadIdx.x;           // 5*384*640
  if (idx >= NLAYER * N2P * N1) return;
  int l = idx / (N2P * N1); int r = idx % (N2P * N1);
  int n = r / N1; int k = r % N1;
  float v = (n < 300 && k < 600) ? W2[(size_t)(l * 600 + k) * 300 + n] : 0.f;
  W2T[idx] = __float2bfloat16(v);
}

__global__ void prep_bias(const float* __restrict__ b1, const float* __restrict__ b2,
                          float* __restrict__ b1p, float* __restrict__ b2p) {
  int idx = blockIdx.x * 256 + threadIdx.x;
  if (idx < NLAYER * N1) {
    int l = idx / N1, n = idx % N1;
    b1p[idx] = (n < 600) ? b1[l * 600 + n] : 0.f;
  } else {
    int k = idx - NLAYER * N1;
    if (k < NLAYER * N2P) {
      int l = k / N2P, n = k % N2P;
      b2p[k] = (n < 300) ? b2[l * 300 + n] : 0.f;
    }
  }
}

// edge-embedding tables for ALL layers: etabg[l][c][ch], c=0..12 (12 combos + self)
__global__ void prep_etab(const float* __restrict__ bond0, const float* __restrict__ bond1,
                          float* __restrict__ etabg) {
  int idx = blockIdx.x * 256 + threadIdx.x;
  if (idx >= NLAYER * 13 * HS) return;
  int l = idx / (13 * HS); int r = idx % (13 * HS);
  int c = r / HS; int ch = r % HS;
  float val = 0.f;
  if (ch < EMB) {
    int t0 = (c < 12) ? (c / 3) : 4;     // self-loop: bond type 4, dir 0
    int t1 = (c < 12) ? (c % 3) : 0;
    val = bond0[(size_t)(l * 6 + t0) * EMB + ch] + bond1[(size_t)(l * 3 + t1) * EMB + ch];
  }
  etabg[idx] = val;
}

__global__ void init_h(const int* __restrict__ x, const float* __restrict__ ae0,
                       const float* __restrict__ ae1, __hip_bfloat16* __restrict__ h) {
  int v = blockIdx.x; int t = threadIdx.x;
  int x0 = x[2 * v], x1 = x[2 * v + 1];
  for (int c = t; c < HS; c += 256)
    h[(size_t)v * HS + c] = __float2bfloat16(c < EMB ? ae0[x0 * EMB + c] + ae1[x1 * EMB + c] : 0.f);
}

// ---------------- CSR build ----------------

__global__ void count_edges(const int* __restrict__ ei, int* __restrict__ counts) {
  int j = blockIdx.x * 256 + threadIdx.x;
  if (j >= NE) return;
  atomicAdd(&counts[ei[NE + j]], 1);
}

__global__ void scan_block(const int* __restrict__ counts, int* __restrict__ indptr,
                           int* __restrict__ blockSums) {
  __shared__ int s[256];
  int b = blockIdx.x, t = threadIdx.x;
  int base = b * 1024 + t * 4;
  int4 c = *(const int4*)&counts[base];
  int tsum = c.x + c.y + c.z + c.w;
  s[t] = tsum;
  __syncthreads();
  for (int off = 1; off < 256; off <<= 1) {
    int v = (t >= off) ? s[t - off] : 0;
    __syncthreads();
    s[t] += v;
    __syncthreads();
  }
  int excl = (t == 0) ? 0 : s[t - 1];
  indptr[base + 0] = excl;
  indptr[base + 1] = excl + c.x;
  indptr[base + 2] = excl + c.x + c.y;
  indptr[base + 3] = excl + c.x + c.y + c.z;
  if (t == 255) blockSums[b] = s[255];
}

__global__ void scan_top(const int* __restrict__ blockSums, int* __restrict__ blockOff) {
  __shared__ int s[128];
  int t = threadIdx.x;
  s[t] = blockSums[t];
  __syncthreads();
  for (int off = 1; off < 128; off <<= 1) {
    int v = (t >= off) ? s[t - off] : 0;
    __syncthreads();
    s[t] += v;
    __syncthreads();
  }
  blockOff[t] = (t == 0) ? 0 : s[t - 1];
}

__global__ void scan_add(int* __restrict__ indptr, const int* __restrict__ blockOff) {
  int b = blockIdx.x, t = threadIdx.x;
  int off = blockOff[b];
  int base = b * 1024 + t * 4;
  indptr[base + 0] += off; indptr[base + 1] += off;
  indptr[base + 2] += off; indptr[base + 3] += off;
  if (b == 127 && t == 255) indptr[NN] = NE;
}

__global__ void scatter_edges(const int* __restrict__ ei, const int* __restrict__ ea,
                              int* __restrict__ cursor, int* __restrict__ epacked) {
  int j = blockIdx.x * 256 + threadIdx.x;
  if (j >= NE) return;
  int dst = ei[NE + j];
  int src = ei[j];
  int c = ea[2 * j] * 3 + ea[2 * j + 1];   // 0..11
  int pos = atomicAdd(&cursor[dst], 1);
  epacked[pos] = src | (c << 17);
}

__global__ void last_idx_kernel(const int* __restrict__ batch, int* __restrict__ lastidx) {
  int i = blockIdx.x * 256 + threadIdx.x;
  if (i >= NN) return;
  int b = batch[i];
  if (i == NN - 1 || batch[i + 1] != b) lastidx[b] = i;
}

// ---------------- aggregate (fused BN-apply + ReLU of previous layer) ----------------
template<int BN>
__global__ __launch_bounds__(1024)
void aggregate_kernel(const __hip_bfloat16* __restrict__ hg, const int* __restrict__ indptr,
                      const int* __restrict__ epacked, const float* __restrict__ etabg,
                      const float* __restrict__ bnsc, const float* __restrict__ bnsh,
                      __hip_bfloat16* __restrict__ agg) {
  __shared__ float etab[13 * HS];
  const int tid = threadIdx.x;
#pragma unroll
  for (int idx = tid; idx < 13 * HS; idx += 1024)
    etab[idx] = etabg[idx];
  __syncthreads();
  const int wid = tid >> 6, lane = tid & 63;
  const int cA = lane * 4, cB = 256 + lane;
  const unsigned short* h = (const unsigned short*)hg;

  f32x4 scA = {1.f, 1.f, 1.f, 1.f}, shA = {0.f, 0.f, 0.f, 0.f};
  float scB = 1.f, shB = 0.f;
  if (BN) {
    scA = *(const f32x4*)&bnsc[cA]; shA = *(const f32x4*)&bnsh[cA];
    scB = bnsc[cB]; shB = bnsh[cB];
  }
  auto trA = [&](float x, int k) -> float {
    if (BN) x = fmaxf(fmaf(x, scA[k], shA[k]), 0.f);
    return x;
  };
  auto trB = [&](float x) -> float {
    if (BN) x = fmaxf(fmaf(x, scB, shB), 0.f);
    return x;
  };
  const float* es = etab + 12 * HS;

  for (int it = 0; it < 4; ++it) {
    const int v = blockIdx.x * 64 + it * 16 + wid;
    const unsigned short* hv = h + (size_t)v * HS;
    ushort4v pA = *(const ushort4v*)(hv + cA);
    unsigned short pB = hv[cB];
    float a0 = trA(b2f(pA[0]), 0) + es[cA];
    float a1 = trA(b2f(pA[1]), 1) + es[cA + 1];
    float a2 = trA(b2f(pA[2]), 2) + es[cA + 2];
    float a3 = trA(b2f(pA[3]), 3) + es[cA + 3];
    float a4 = trB(b2f(pB)) + es[cB];

    const int jb = indptr[v], je = indptr[v + 1];
    int j = jb;
    for (; j + 2 <= je; j += 2) {
      int p0 = epacked[j], p1 = epacked[j + 1];
      const unsigned short* h0 = h + (size_t)(p0 & (NN - 1)) * HS;
      const unsigned short* h1 = h + (size_t)(p1 & (NN - 1)) * HS;
      ushort4v q0 = *(const ushort4v*)(h0 + cA);
      ushort4v q1 = *(const ushort4v*)(h1 + cA);
      unsigned short r0 = h0[cB], r1 = h1[cB];
      const float* e0 = etab + (p0 >> 17) * HS;
      const float* e1 = etab + (p1 >> 17) * HS;
      a0 += trA(b2f(q0[0]), 0) + e0[cA]     + trA(b2f(q1[0]), 0) + e1[cA];
      a1 += trA(b2f(q0[1]), 1) + e0[cA + 1] + trA(b2f(q1[1]), 1) + e1[cA + 1];
      a2 += trA(b2f(q0[2]), 2) + e0[cA + 2] + trA(b2f(q1[2]), 2) + e1[cA + 2];
      a3 += trA(b2f(q0[3]), 3) + e0[cA + 3] + trA(b2f(q1[3]), 3) + e1[cA + 3];
      a4 += trB(b2f(r0)) + e0[cB] + trB(b2f(r1)) + e1[cB];
    }
    if (j < je) {
      int p0 = epacked[j];
      const unsigned short* h0 = h + (size_t)(p0 & (NN - 1)) * HS;
      ushort4v q0 = *(const ushort4v*)(h0 + cA);
      unsigned short r0 = h0[cB];
      const float* e0 = etab + (p0 >> 17) * HS;
      a0 += trA(b2f(q0[0]), 0) + e0[cA];
      a1 += trA(b2f(q0[1]), 1) + e0[cA + 1];
      a2 += trA(b2f(q0[2]), 2) + e0[cA + 2];
      a3 += trA(b2f(q0[3]), 3) + e0[cA + 3];
      a4 += trB(b2f(r0)) + e0[cB];
    }

    unsigned short* av = (unsigned short*)agg + (size_t)v * HS;
    ushort4v o; o[0] = f2b(a0); o[1] = f2b(a1); o[2] = f2b(a2); o[3] = f2b(a3);
    *(ushort4v*)(av + cA) = o;
    av[cB] = f2b(a4);
  }
}

// ---------------- GEMM ----------------
// R12 skeleton + CH=2 m-tile chaining: one block computes 2 stacked 128x128
// output tiles (same bn). The K-loop runs 2*NT continuous steps; prologue fill
// is paid once, and the tile-0 epilogue runs with tile-1's prefetch in flight
// (epilogue uses no K-loop LDS; STATS barriers are lgkm-only). Grids stay
// >=1280 blocks (5/CU waves) so R7's parallelism collapse is avoided.
// 3-buffer LDS (48 KB), ONE barrier/step, counted vmcnt(4), compile-time K,
// XOR-swizzled k-slots (dest linear per rule #21), XCD-bijective remap.
template<int RELU, int STATS, int NBN, int KSTRIDE, int KEXT>
__global__ __launch_bounds__(256)
void gemm_kernel(const short* __restrict__ A, const short* __restrict__ BT,
                 const float* __restrict__ bias, __hip_bfloat16* __restrict__ Cout,
                 float* __restrict__ part, int outStride, int outBound, int rbBase) {
  __shared__ short smem[3 * 8192];     // 3 x (A 4096 + B 4096 shorts) = 48 KB
  __shared__ float sred[STATS ? 128 : 1][2];
  const int tid = threadIdx.x;
  const int wid = tid >> 6, lane = tid & 63;
  const int wm = wid >> 1, wn = wid & 1;

  // XCD-bijective remap (gridDim.x % 8 == 0 in all launch configs)
  const int cpx = gridDim.x >> 3;
  const int logical = (blockIdx.x & 7) * cpx + (blockIdx.x >> 3);
  const int bn = logical % NBN;
  const int chain = logical / NBN;     // 2 stacked m-tiles per chain

  const short* Ag = A + (size_t)(chain * CH) * 128 * KSTRIDE;
  const short* Bg = BT + (size_t)bn * 128 * KSTRIDE;
  const int r2 = tid >> 2;                                   // staged row 0..63
  const int ksw = ((tid & 3) ^ ((tid >> 3) & 3)) * 8;        // swizzled k-src (shorts)
  const int arow_h = lane & 15;                              // read row within 16
  const int koffR = (((lane >> 4) ^ ((arow_h >> 1) & 3)) * 8);  // swizzled k-read (shorts)

  const short* Ao = Ag + (size_t)r2 * KSTRIDE + ksw;
  const short* Bo = Bg + (size_t)r2 * KSTRIDE + ksw;

  constexpr int NT = KEXT / 32;
  constexpr int GT = NT * CH;

  auto stage = [&](int g) {            // global step index 0..GT-1 (compile-time)
    const int mt = g / NT;
    const int kt = (g % NT) * 32;
    short* s = smem + (g % 3) * 8192;
    gload_lds16(Ao + mt * 128 * KSTRIDE + kt,                s + tid * 8);
    gload_lds16(Ao + mt * 128 * KSTRIDE + kt + 64 * KSTRIDE, s + 2048 + tid * 8);
    gload_lds16(Bo + kt,                                     s + 4096 + tid * 8);
    gload_lds16(Bo + kt + 64 * KSTRIDE,                      s + 6144 + tid * 8);
  };

  const int col0 = bn * 128 + wn * 64 + (lane & 15);
  float bs[4];
#pragma unroll
  for (int j = 0; j < 4; j++) bs[j] = bias[col0 + j * 16];

  stage(0);
  stage(1);
#pragma unroll
  for (int mt = 0; mt < CH; ++mt) {
    f32x4 acc[4][4] = {};
#pragma unroll
    for (int k = 0; k < NT; ++k) {
      const int g = mt * NT + k;
      if (g + 1 < GT) asm volatile("s_waitcnt vmcnt(4)" ::: "memory");
      else            asm volatile("s_waitcnt vmcnt(0)" ::: "memory");
      __builtin_amdgcn_sched_barrier(0);
      __builtin_amdgcn_s_barrier();
      if (g + 2 < GT) stage(g + 2);
      const short* sA = smem + (g % 3) * 8192 + wm * 2048;
      const short* sB = smem + (g % 3) * 8192 + 4096 + wn * 2048;
      short8 af[4], bf[4];
#pragma unroll
      for (int i = 0; i < 4; i++) af[i] = *(const short8*)&sA[(arow_h + i * 16) * 32 + koffR];
#pragma unroll
      for (int j = 0; j < 4; j++) bf[j] = *(const short8*)&sB[(arow_h + j * 16) * 32 + koffR];
#pragma unroll
      for (int i = 0; i < 4; i++)
#pragma unroll
        for (int j = 0; j < 4; j++)
          acc[i][j] = __builtin_amdgcn_mfma_f32_16x16x32_bf16(af[i], bf[j], acc[i][j], 0, 0, 0);
      __builtin_amdgcn_sched_barrier(0);
    }

    // ---- epilogue for m-tile mt (no vmcnt drain; prefetch stays in flight) ----
    const int bm = chain * CH + mt;
    const int row0 = bm * 128 + wm * 64 + (lane >> 4) * 4;
    float ssum[4] = {0, 0, 0, 0}, ssq[4] = {0, 0, 0, 0};
    if (STATS) {
      if (tid < 128) { sred[tid][0] = 0.f; sred[tid][1] = 0.f; }
      asm volatile("s_waitcnt lgkmcnt(0)" ::: "memory");
      __builtin_amdgcn_s_barrier();
    }
#pragma unroll
    for (int i = 0; i < 4; i++) {
#pragma unroll
      for (int p = 0; p < 4; p++) {
        const size_t row = row0 + i * 16 + p;
#pragma unroll
        for (int j = 0; j < 4; j++) {
          const int col = col0 + j * 16;
          float v = acc[i][j][p] + bs[j];
          if (STATS) { ssum[j] += v; ssq[j] += v * v; }
          if (RELU) v = fmaxf(v, 0.f);
          if (col < outBound)
            Cout[row * (size_t)outStride + col] = __float2bfloat16(v);
        }
      }
    }
    if (STATS) {
#pragma unroll
      for (int j = 0; j < 4; j++) {
        const int cw = wn * 64 + j * 16 + (lane & 15);
        atomicAdd(&sred[cw][0], ssum[j]);
        atomicAdd(&sred[cw][1], ssq[j]);
      }
      asm volatile("s_waitcnt lgkmcnt(0)" ::: "memory");
      __builtin_amdgcn_s_barrier();
      if (tid < 128) {
        const int col = bn * 128 + tid;
        if (col < EMB) {
          part[(size_t)col * (2 * NRB) + rbBase + bm] = sred[tid][0];
          part[(size_t)col * (2 * NRB) + NRB + rbBase + bm] = sred[tid][1];
        }
      }
      __builtin_amdgcn_s_barrier();   // sred reused by next m-tile
    }
  }
}

// ---------------- BN finalize: partials -> scale/shift ----------------
__global__ __launch_bounds__(256)
void bn_finalize(const float* __restrict__ part, const float* __restrict__ gamma,
                 const float* __restrict__ beta, float* __restrict__ bnsc,
                 float* __restrict__ bnsh) {
  __shared__ float rs[256], rq[256];
  const int c = blockIdx.x, t = threadIdx.x;
  if (c >= EMB) {
    if (t == 0) { bnsc[c] = 0.f; bnsh[c] = 0.f; }
    return;
  }
  float s = 0.f, q = 0.f;
  for (int rb = t; rb < NRB; rb += 256) {
    s += part[(size_t)c * (2 * NRB) + rb];
    q += part[(size_t)c * (2 * NRB) + NRB + rb];
  }
  rs[t] = s; rq[t] = q;
  __syncthreads();
  for (int off = 128; off > 0; off >>= 1) {
    if (t < off) { rs[t] += rs[t + off]; rq[t] += rq[t + off]; }
    __syncthreads();
  }
  if (t == 0) {
    float mean = rs[0] / (float)NN;
    float var = rq[0] / (float)NN - mean * mean;
    float sc = rsqrtf(var + 1e-5f) * gamma[c];
    bnsc[c] = sc;
    bnsh[c] = beta[c] - mean * sc;
  }
}

// ---------------- head (applies final BN, no relu) ----------------
__global__ __launch_bounds__(256)
void head_kernel(const __hip_bfloat16* __restrict__ h, const int* __restrict__ lastidx,
                 const float* __restrict__ bnsc4, const float* __restrict__ bnsh4,
                 const float* __restrict__ hW1, const float* __restrict__ hb1,
                 const float* __restrict__ hW2, const float* __restrict__ hb2,
                 float* __restrict__ out) {
  __shared__ float sup[EMB];
  __shared__ float red[256];
  int g = blockIdx.x, t = threadIdx.x;
  int v = lastidx[g];
  for (int c = t; c < EMB; c += 256)
    sup[c] = b2f(((const unsigned short*)h)[(size_t)v * HS + c]) * bnsc4[c] + bnsh4[c];
  __syncthreads();
  float val = 0.f;
  if (t < 150) {
    float acc = hb1[t];
    for (int k = 0; k < EMB; k++) acc += sup[k] * hW1[k * 150 + t];
    float e = (acc > 0.f) ? acc : (expf(acc) - 1.f);   // elu
    val = e * hW2[t];
  }
  red[t] = val;
  __syncthreads();
  for (int off = 128; off > 0; off >>= 1) {
    if (t < off) red[t] += red[t + off];
    __syncthreads();
  }
  if (t == 0) out[g] = red[0] + hb2[0];
}

// ---------------- host ----------------

extern "C" void kernel_launch(void* const* d_in, const int* in_sizes, int n_in,
                              void* d_out, int out_size, void* d_ws, size_t ws_size,
                              hipStream_t stream) {
  const int* x      = (const int*)d_in[0];
  const int* ei     = (const int*)d_in[1];
  const int* ea     = (const int*)d_in[2];
  const int* batch  = (const int*)d_in[3];
  // d_in[4] = num_graphs (static)
  const float* atom0 = (const float*)d_in[5];
  const float* atom1 = (const float*)d_in[6];
  const float* bond0 = (const float*)d_in[7];
  const float* bond1 = (const float*)d_in[8];
  const float* W1    = (const float*)d_in[9];
  const float* b1    = (const float*)d_in[10];
  const float* W2    = (const float*)d_in[11];
  const float* b2    = (const float*)d_in[12];
  const float* gamma = (const float*)d_in[13];
  const float* beta  = (const float*)d_in[14];
  const float* hW1   = (const float*)d_in[15];
  const float* hb1   = (const float*)d_in[16];
  const float* hW2   = (const float*)d_in[17];
  const float* hb2   = (const float*)d_in[18];
  float* out = (float*)d_out;

  char* p = (char*)d_ws;
  auto carve = [&](size_t b) -> void* {
    void* r = (void*)p;
    p += (b + 255) & ~(size_t)255;
    return r;
  };
  // fixed buffers (~176 MB)
  __hip_bfloat16* agg = (__hip_bfloat16*)carve((size_t)NN * HS * 2);        // 80 MB
  __hip_bfloat16* h   = (__hip_bfloat16*)carve((size_t)NN * HS * 2);        // 80 MB
  __hip_bfloat16* W1T = (__hip_bfloat16*)carve((size_t)NLAYER * N1 * K1 * 2);
  __hip_bfloat16* W2T = (__hip_bfloat16*)carve((size_t)NLAYER * N2P * N1 * 2);
  float* b1p          = (float*)carve((size_t)NLAYER * N1 * 4);
  float* b2p          = (float*)carve((size_t)NLAYER * N2P * 4);
  float* etabg        = (float*)carve((size_t)NLAYER * 13 * HS * 4);        // 83 KB
  float* part         = (float*)carve((size_t)EMB * 2 * NRB * 4);           // 2.4 MB
  float* bnsc         = (float*)carve((size_t)NLAYER * HS * 4);
  float* bnsh         = (float*)carve((size_t)NLAYER * HS * 4);
  int* counts         = (int*)carve((size_t)NN * 4);
  int* indptr         = (int*)carve((size_t)(NN + 1) * 4);
  int* cursor         = (int*)carve((size_t)NN * 4);
  int* epacked        = (int*)carve((size_t)NE * 4);
  int* blockSums      = (int*)carve(128 * 4);
  int* blockOff       = (int*)carve(128 * 4);
  int* lastidx        = (int*)carve((size_t)NG * 4);

  size_t used = (size_t)(p - (char*)d_ws);
  size_t avail = (ws_size > used + 4096) ? (ws_size - used - 4096) : 0;
  int CHUNK = 16384;   // 20 MB — known-good floor
  if (avail >= (size_t)65536 * N1 * 2) CHUNK = 65536;         // 80 MB (R12 best-known)
  else if (avail >= (size_t)32768 * N1 * 2) CHUNK = 32768;    // 40 MB
  __hip_bfloat16* hid = (__hip_bfloat16*)carve((size_t)CHUNK * N1 * 2);

  hipMemsetAsync(counts, 0, (size_t)NN * 4, stream);

  prep_w1<<<(NLAYER * N1 * K1 + 255) / 256, 256, 0, stream>>>(W1, W1T);
  prep_w2<<<(NLAYER * N2P * N1 + 255) / 256, 256, 0, stream>>>(W2, W2T);
  prep_bias<<<(NLAYER * (N1 + N2P) + 255) / 256, 256, 0, stream>>>(b1, b2, b1p, b2p);
  prep_etab<<<(NLAYER * 13 * HS + 255) / 256, 256, 0, stream>>>(bond0, bond1, etabg);
  init_h<<<NN, 256, 0, stream>>>(x, atom0, atom1, h);

  count_edges<<<NE / 256, 256, 0, stream>>>(ei, counts);
  scan_block<<<128, 256, 0, stream>>>(counts, indptr, blockSums);
  scan_top<<<1, 128, 0, stream>>>(blockSums, blockOff);
  scan_add<<<128, 256, 0, stream>>>(indptr, blockOff);
  hipMemcpyAsync(cursor, indptr, (size_t)NN * 4, hipMemcpyDeviceToDevice, stream);
  scatter_edges<<<NE / 256, 256, 0, stream>>>(ei, ea, cursor, epacked);
  last_idx_kernel<<<NN / 256, 256, 0, stream>>>(batch, lastidx);

  for (int l = 0; l < NLAYER; l++) {
    if (l == 0)
      aggregate_kernel<0><<<NN / 64, 1024, 0, stream>>>(
          h, indptr, epacked, etabg + (size_t)l * 13 * HS, nullptr, nullptr, agg);
    else
      aggregate_kernel<1><<<NN / 64, 1024, 0, stream>>>(
          h, indptr, epacked, etabg + (size_t)l * 13 * HS,
          bnsc + (size_t)(l - 1) * HS, bnsh + (size_t)(l - 1) * HS, agg);
    for (int c0 = 0; c0 < NN; c0 += CHUNK) {
      gemm_kernel<1, 0, N1 / 128, K1, K1><<<(CHUNK / (128 * CH)) * (N1 / 128), 256, 0, stream>>>(
          (const short*)(agg + (size_t)c0 * HS),
          (const short*)(W1T + (size_t)l * N1 * K1), b1p + l * N1,
          hid, nullptr, N1, N1, 0);
      gemm_kernel<0, 1, N2P / 128, N1, K2E><<<(CHUNK / (128 * CH)) * (N2P / 128), 256, 0, stream>>>(
          (const short*)hid,
          (const short*)(W2T + (size_t)l * N2P * N1), b2p + l * N2P,
          h + (size_t)c0 * HS, part, HS, HS, c0 / 128);
    }
    bn_finalize<<<HS, 256, 0, stream>>>(part, gamma + (size_t)l * EMB, beta + (size_t)l * EMB,
                                        bnsc + (size_t)l * HS, bnsh + (size_t)l * HS);
  }

  head_kernel<<<NG, 256, 0, stream>>>(h, lastidx, bnsc + 4 * HS, bnsh + 4 * HS,
                                      hW1, hb1, hW2, hb2, out);
}

// Round 16
// 1659.727 us; speedup vs baseline: 1.1488x; 1.1488x over previous
//
#include <hip/hip_runtime.h>
#include <hip/hip_bf16.h>

#define NN 131072      // nodes
#define NE 262144      // edges (without self loops)
#define NG 4096        // graphs
#define EMB 300
#define HS 320         // h/agg row stride (bf16, padded, cols 300..319 == 0)
#define K1 320         // GEMM1 K
#define N1 640         // padded 600 (GEMM1 out / hid stride / GEMM2 K stride)
#define K2E 608        // GEMM2 K extent (cols 600..639 of hid are exact zeros)
#define N2P 384        // padded 300 (GEMM2 B rows)
#define NLAYER 5
#define NRB (NN / 128) // 1024 row-blocks for BN partials

typedef __attribute__((ext_vector_type(8))) short short8;
typedef __attribute__((ext_vector_type(4))) float f32x4;
typedef __attribute__((ext_vector_type(4))) unsigned short ushort4v;

__device__ __forceinline__ void gload_lds16(const void* g, void* l) {
  __builtin_amdgcn_global_load_lds((const __attribute__((address_space(1))) void*)g,
                                   (__attribute__((address_space(3))) void*)l, 16, 0, 0);
}
__device__ __forceinline__ float b2f(unsigned short u) {
  return __uint_as_float(((unsigned)u) << 16);
}
__device__ __forceinline__ unsigned short f2b(float x) {
  __hip_bfloat16 b = __float2bfloat16(x);
  return *(unsigned short*)&b;
}

// ---------------- prep kernels ----------------

__global__ void prep_w1(const float* __restrict__ W1, __hip_bfloat16* __restrict__ W1T) {
  int idx = blockIdx.x * 256 + threadIdx.x;           // 5*640*320
  if (idx >= NLAYER * N1 * K1) return;
  int l = idx / (N1 * K1); int r = idx % (N1 * K1);
  int n = r / K1; int k = r % K1;
  float v = (n < 600 && k < 300) ? W1[(size_t)(l * 300 + k) * 600 + n] : 0.f;
  W1T[idx] = __float2bfloat16(v);
}

__global__ void prep_w2(const float* __restrict__ W2, __hip_bfloat16* __restrict__ W2T) {
  int idx = blockIdx.x * 256 + threadIdx.x;           // 5*384*640
  if (idx >= NLAYER * N2P * N1) return;
  int l = idx / (N2P * N1); int r = idx % (N2P * N1);
  int n = r / N1; int k = r % N1;
  float v = (n < 300 && k < 600) ? W2[(size_t)(l * 600 + k) * 300 + n] : 0.f;
  W2T[idx] = __float2bfloat16(v);
}

__global__ void prep_bias(const float* __restrict__ b1, const float* __restrict__ b2,
                          float* __restrict__ b1p, float* __restrict__ b2p) {
  int idx = blockIdx.x * 256 + threadIdx.x;
  if (idx < NLAYER * N1) {
    int l = idx / N1, n = idx % N1;
    b1p[idx] = (n < 600) ? b1[l * 600 + n] : 0.f;
  } else {
    int k = idx - NLAYER * N1;
    if (k < NLAYER * N2P) {
      int l = k / N2P, n = k % N2P;
      b2p[k] = (n < 300) ? b2[l * 300 + n] : 0.f;
    }
  }
}

// edge-embedding tables for ALL layers: etabg[l][c][ch], c=0..12 (12 combos + self)
__global__ void prep_etab(const float* __restrict__ bond0, const float* __restrict__ bond1,
                          float* __restrict__ etabg) {
  int idx = blockIdx.x * 256 + threadIdx.x;
  if (idx >= NLAYER * 13 * HS) return;
  int l = idx / (13 * HS); int r = idx % (13 * HS);
  int c = r / HS; int ch = r % HS;
  float val = 0.f;
  if (ch < EMB) {
    int t0 = (c < 12) ? (c / 3) : 4;     // self-loop: bond type 4, dir 0
    int t1 = (c < 12) ? (c % 3) : 0;
    val = bond0[(size_t)(l * 6 + t0) * EMB + ch] + bond1[(size_t)(l * 3 + t1) * EMB + ch];
  }
  etabg[idx] = val;
}

__global__ void init_h(const int* __restrict__ x, const float* __restrict__ ae0,
                       const float* __restrict__ ae1, __hip_bfloat16* __restrict__ h) {
  int v = blockIdx.x; int t = threadIdx.x;
  int x0 = x[2 * v], x1 = x[2 * v + 1];
  for (int c = t; c < HS; c += 256)
    h[(size_t)v * HS + c] = __float2bfloat16(c < EMB ? ae0[x0 * EMB + c] + ae1[x1 * EMB + c] : 0.f);
}

// ---------------- CSR build ----------------

__global__ void count_edges(const int* __restrict__ ei, int* __restrict__ counts) {
  int j = blockIdx.x * 256 + threadIdx.x;
  if (j >= NE) return;
  atomicAdd(&counts[ei[NE + j]], 1);
}

__global__ void scan_block(const int* __restrict__ counts, int* __restrict__ indptr,
                           int* __restrict__ blockSums) {
  __shared__ int s[256];
  int b = blockIdx.x, t = threadIdx.x;
  int base = b * 1024 + t * 4;
  int4 c = *(const int4*)&counts[base];
  int tsum = c.x + c.y + c.z + c.w;
  s[t] = tsum;
  __syncthreads();
  for (int off = 1; off < 256; off <<= 1) {
    int v = (t >= off) ? s[t - off] : 0;
    __syncthreads();
    s[t] += v;
    __syncthreads();
  }
  int excl = (t == 0) ? 0 : s[t - 1];
  indptr[base + 0] = excl;
  indptr[base + 1] = excl + c.x;
  indptr[base + 2] = excl + c.x + c.y;
  indptr[base + 3] = excl + c.x + c.y + c.z;
  if (t == 255) blockSums[b] = s[255];
}

__global__ void scan_top(const int* __restrict__ blockSums, int* __restrict__ blockOff) {
  __shared__ int s[128];
  int t = threadIdx.x;
  s[t] = blockSums[t];
  __syncthreads();
  for (int off = 1; off < 128; off <<= 1) {
    int v = (t >= off) ? s[t - off] : 0;
    __syncthreads();
    s[t] += v;
    __syncthreads();
  }
  blockOff[t] = (t == 0) ? 0 : s[t - 1];
}

__global__ void scan_add(int* __restrict__ indptr, const int* __restrict__ blockOff) {
  int b = blockIdx.x, t = threadIdx.x;
  int off = blockOff[b];
  int base = b * 1024 + t * 4;
  indptr[base + 0] += off; indptr[base + 1] += off;
  indptr[base + 2] += off; indptr[base + 3] += off;
  if (b == 127 && t == 255) indptr[NN] = NE;
}

__global__ void scatter_edges(const int* __restrict__ ei, const int* __restrict__ ea,
                              int* __restrict__ cursor, int* __restrict__ epacked) {
  int j = blockIdx.x * 256 + threadIdx.x;
  if (j >= NE) return;
  int dst = ei[NE + j];
  int src = ei[j];
  int c = ea[2 * j] * 3 + ea[2 * j + 1];   // 0..11
  int pos = atomicAdd(&cursor[dst], 1);
  epacked[pos] = src | (c << 17);
}

__global__ void last_idx_kernel(const int* __restrict__ batch, int* __restrict__ lastidx) {
  int i = blockIdx.x * 256 + threadIdx.x;
  if (i >= NN) return;
  int b = batch[i];
  if (i == NN - 1 || batch[i + 1] != b) lastidx[b] = i;
}

// ---------------- aggregate (fused BN-apply + ReLU of previous layer) ----------------
// etab copied from precomputed global table; 64 nodes/block (4 per wave);
// 2-wide edge unroll (28 VGPR — R7's 4-wide cost occupancy).
template<int BN>
__global__ __launch_bounds__(1024)
void aggregate_kernel(const __hip_bfloat16* __restrict__ hg, const int* __restrict__ indptr,
                      const int* __restrict__ epacked, const float* __restrict__ etabg,
                      const float* __restrict__ bnsc, const float* __restrict__ bnsh,
                      __hip_bfloat16* __restrict__ agg) {
  __shared__ float etab[13 * HS];
  const int tid = threadIdx.x;
#pragma unroll
  for (int idx = tid; idx < 13 * HS; idx += 1024)
    etab[idx] = etabg[idx];
  __syncthreads();
  const int wid = tid >> 6, lane = tid & 63;
  const int cA = lane * 4, cB = 256 + lane;
  const unsigned short* h = (const unsigned short*)hg;

  f32x4 scA = {1.f, 1.f, 1.f, 1.f}, shA = {0.f, 0.f, 0.f, 0.f};
  float scB = 1.f, shB = 0.f;
  if (BN) {
    scA = *(const f32x4*)&bnsc[cA]; shA = *(const f32x4*)&bnsh[cA];
    scB = bnsc[cB]; shB = bnsh[cB];
  }
  auto trA = [&](float x, int k) -> float {
    if (BN) x = fmaxf(fmaf(x, scA[k], shA[k]), 0.f);
    return x;
  };
  auto trB = [&](float x) -> float {
    if (BN) x = fmaxf(fmaf(x, scB, shB), 0.f);
    return x;
  };
  const float* es = etab + 12 * HS;

  for (int it = 0; it < 4; ++it) {
    const int v = blockIdx.x * 64 + it * 16 + wid;
    const unsigned short* hv = h + (size_t)v * HS;
    ushort4v pA = *(const ushort4v*)(hv + cA);
    unsigned short pB = hv[cB];
    float a0 = trA(b2f(pA[0]), 0) + es[cA];
    float a1 = trA(b2f(pA[1]), 1) + es[cA + 1];
    float a2 = trA(b2f(pA[2]), 2) + es[cA + 2];
    float a3 = trA(b2f(pA[3]), 3) + es[cA + 3];
    float a4 = trB(b2f(pB)) + es[cB];

    const int jb = indptr[v], je = indptr[v + 1];
    int j = jb;
    for (; j + 2 <= je; j += 2) {
      int p0 = epacked[j], p1 = epacked[j + 1];
      const unsigned short* h0 = h + (size_t)(p0 & (NN - 1)) * HS;
      const unsigned short* h1 = h + (size_t)(p1 & (NN - 1)) * HS;
      ushort4v q0 = *(const ushort4v*)(h0 + cA);
      ushort4v q1 = *(const ushort4v*)(h1 + cA);
      unsigned short r0 = h0[cB], r1 = h1[cB];
      const float* e0 = etab + (p0 >> 17) * HS;
      const float* e1 = etab + (p1 >> 17) * HS;
      a0 += trA(b2f(q0[0]), 0) + e0[cA]     + trA(b2f(q1[0]), 0) + e1[cA];
      a1 += trA(b2f(q0[1]), 1) + e0[cA + 1] + trA(b2f(q1[1]), 1) + e1[cA + 1];
      a2 += trA(b2f(q0[2]), 2) + e0[cA + 2] + trA(b2f(q1[2]), 2) + e1[cA + 2];
      a3 += trA(b2f(q0[3]), 3) + e0[cA + 3] + trA(b2f(q1[3]), 3) + e1[cA + 3];
      a4 += trB(b2f(r0)) + e0[cB] + trB(b2f(r1)) + e1[cB];
    }
    if (j < je) {
      int p0 = epacked[j];
      const unsigned short* h0 = h + (size_t)(p0 & (NN - 1)) * HS;
      ushort4v q0 = *(const ushort4v*)(h0 + cA);
      unsigned short r0 = h0[cB];
      const float* e0 = etab + (p0 >> 17) * HS;
      a0 += trA(b2f(q0[0]), 0) + e0[cA];
      a1 += trA(b2f(q0[1]), 1) + e0[cA + 1];
      a2 += trA(b2f(q0[2]), 2) + e0[cA + 2];
      a3 += trA(b2f(q0[3]), 3) + e0[cA + 3];
      a4 += trB(b2f(r0)) + e0[cB];
    }

    unsigned short* av = (unsigned short*)agg + (size_t)v * HS;
    ushort4v o; o[0] = f2b(a0); o[1] = f2b(a1); o[2] = f2b(a2); o[3] = f2b(a3);
    *(ushort4v*)(av + cA) = o;
    av[cB] = f2b(a4);
  }
}

// ---------------- GEMM (R12 config — best known — + T5 setprio probe) ----------------
// 128x128 tile, 3-buffer LDS (48 KB, 3 blocks/CU), ONE barrier per K-step,
// counted vmcnt(4) with 2-step prefetch distance, compile-time K geometry
// (KSTRIDE = row stride, KEXT = extent; GEMM2 KEXT=608 skips all-zero pad K),
// XOR-swizzled k-slots (dest linear per rule #21), XCD-bijective remap.
// T5: setprio(1) around the MFMA cluster — blocks on a CU run phase-staggered
// (no inter-block sync), so the scheduler can favor MFMA-issuing waves.
template<int RELU, int STATS, int NBN, int KSTRIDE, int KEXT>
__global__ __launch_bounds__(256)
void gemm_kernel(const short* __restrict__ A, const short* __restrict__ BT,
                 const float* __restrict__ bias, __hip_bfloat16* __restrict__ Cout,
                 float* __restrict__ part, int outStride, int outBound, int rbBase) {
  __shared__ short smem[3 * 8192];     // 3 x (A 4096 + B 4096 shorts) = 48 KB
  __shared__ float sred[STATS ? 128 : 1][2];
  const int tid = threadIdx.x;
  const int wid = tid >> 6, lane = tid & 63;
  const int wm = wid >> 1, wn = wid & 1;
  f32x4 acc[4][4] = {};

  // XCD-bijective remap (gridDim.x % 8 == 0 in all launch configs)
  const int cpx = gridDim.x >> 3;
  const int logical = (blockIdx.x & 7) * cpx + (blockIdx.x >> 3);
  const int bn = logical % NBN;
  const int bm = logical / NBN;

  const short* Ag = A + (size_t)bm * 128 * KSTRIDE;
  const short* Bg = BT + (size_t)bn * 128 * KSTRIDE;
  const int r2 = tid >> 2;                                   // staged row 0..63
  const int ksw = ((tid & 3) ^ ((tid >> 3) & 3)) * 8;        // swizzled k-src (shorts)
  const int arow_h = lane & 15;                              // read row within 16
  const int koffR = (((lane >> 4) ^ ((arow_h >> 1) & 3)) * 8);  // swizzled k-read (shorts)

  const short* Ao = Ag + (size_t)r2 * KSTRIDE + ksw;
  const short* Bo = Bg + (size_t)r2 * KSTRIDE + ksw;

  auto stage = [&](int buf, int kt) {
    short* s = smem + buf * 8192;
    gload_lds16(Ao + kt,                 s + tid * 8);
    gload_lds16(Ao + kt + 64 * KSTRIDE,  s + 2048 + tid * 8);
    gload_lds16(Bo + kt,                 s + 4096 + tid * 8);
    gload_lds16(Bo + kt + 64 * KSTRIDE,  s + 6144 + tid * 8);
  };

  constexpr int NT = KEXT / 32;
  stage(0, 0);
  stage(1, 32);
#pragma unroll
  for (int t = 0; t < NT; ++t) {
    if (t + 1 < NT) asm volatile("s_waitcnt vmcnt(4)" ::: "memory");
    else            asm volatile("s_waitcnt vmcnt(0)" ::: "memory");
    __builtin_amdgcn_sched_barrier(0);
    __builtin_amdgcn_s_barrier();
    const int rb = t % 3;
    if (t + 2 < NT) stage((t + 2) % 3, (t + 2) * 32);
    const short* sA = smem + rb * 8192 + wm * 2048;
    const short* sB = smem + rb * 8192 + 4096 + wn * 2048;
    short8 af[4], bf[4];
#pragma unroll
    for (int i = 0; i < 4; i++) af[i] = *(const short8*)&sA[(arow_h + i * 16) * 32 + koffR];
#pragma unroll
    for (int j = 0; j < 4; j++) bf[j] = *(const short8*)&sB[(arow_h + j * 16) * 32 + koffR];
    __builtin_amdgcn_s_setprio(1);
#pragma unroll
    for (int i = 0; i < 4; i++)
#pragma unroll
      for (int j = 0; j < 4; j++)
        acc[i][j] = __builtin_amdgcn_mfma_f32_16x16x32_bf16(af[i], bf[j], acc[i][j], 0, 0, 0);
    __builtin_amdgcn_s_setprio(0);
    __builtin_amdgcn_sched_barrier(0);
  }

  const int row0 = bm * 128 + wm * 64 + (lane >> 4) * 4;
  const int col0 = bn * 128 + wn * 64 + (lane & 15);
  float bs[4];
#pragma unroll
  for (int j = 0; j < 4; j++) bs[j] = bias[col0 + j * 16];
  float ssum[4] = {0, 0, 0, 0}, ssq[4] = {0, 0, 0, 0};
  if (STATS) {
    if (tid < 128) { sred[tid][0] = 0.f; sred[tid][1] = 0.f; }
    __syncthreads();
  }
#pragma unroll
  for (int i = 0; i < 4; i++) {
#pragma unroll
    for (int p = 0; p < 4; p++) {
      const size_t row = row0 + i * 16 + p;
#pragma unroll
      for (int j = 0; j < 4; j++) {
        const int col = col0 + j * 16;
        float v = acc[i][j][p] + bs[j];
        if (STATS) { ssum[j] += v; ssq[j] += v * v; }
        if (RELU) v = fmaxf(v, 0.f);
        if (col < outBound)
          Cout[row * (size_t)outStride + col] = __float2bfloat16(v);
      }
    }
  }
  if (STATS) {
#pragma unroll
    for (int j = 0; j < 4; j++) {
      const int cw = wn * 64 + j * 16 + (lane & 15);
      atomicAdd(&sred[cw][0], ssum[j]);
      atomicAdd(&sred[cw][1], ssq[j]);
    }
    __syncthreads();
    if (tid < 128) {
      const int col = bn * 128 + tid;
      if (col < EMB) {
        const int rb2 = rbBase + bm;
        part[(size_t)col * (2 * NRB) + rb2] = sred[tid][0];
        part[(size_t)col * (2 * NRB) + NRB + rb2] = sred[tid][1];
      }
    }
  }
}

// ---------------- BN finalize: partials -> scale/shift ----------------
__global__ __launch_bounds__(256)
void bn_finalize(const float* __restrict__ part, const float* __restrict__ gamma,
                 const float* __restrict__ beta, float* __restrict__ bnsc,
                 float* __restrict__ bnsh) {
  __shared__ float rs[256], rq[256];
  const int c = blockIdx.x, t = threadIdx.x;
  if (c >= EMB) {
    if (t == 0) { bnsc[c] = 0.f; bnsh[c] = 0.f; }
    return;
  }
  float s = 0.f, q = 0.f;
  for (int rb = t; rb < NRB; rb += 256) {
    s += part[(size_t)c * (2 * NRB) + rb];
    q += part[(size_t)c * (2 * NRB) + NRB + rb];
  }
  rs[t] = s; rq[t] = q;
  __syncthreads();
  for (int off = 128; off > 0; off >>= 1) {
    if (t < off) { rs[t] += rs[t + off]; rq[t] += rq[t + off]; }
    __syncthreads();
  }
  if (t == 0) {
    float mean = rs[0] / (float)NN;
    float var = rq[0] / (float)NN - mean * mean;
    float sc = rsqrtf(var + 1e-5f) * gamma[c];
    bnsc[c] = sc;
    bnsh[c] = beta[c] - mean * sc;
  }
}

// ---------------- head (applies final BN, no relu) ----------------
__global__ __launch_bounds__(256)
void head_kernel(const __hip_bfloat16* __restrict__ h, const int* __restrict__ lastidx,
                 const float* __restrict__ bnsc4, const float* __restrict__ bnsh4,
                 const float* __restrict__ hW1, const float* __restrict__ hb1,
                 const float* __restrict__ hW2, const float* __restrict__ hb2,
                 float* __restrict__ out) {
  __shared__ float sup[EMB];
  __shared__ float red[256];
  int g = blockIdx.x, t = threadIdx.x;
  int v = lastidx[g];
  for (int c = t; c < EMB; c += 256)
    sup[c] = b2f(((const unsigned short*)h)[(size_t)v * HS + c]) * bnsc4[c] + bnsh4[c];
  __syncthreads();
  float val = 0.f;
  if (t < 150) {
    float acc = hb1[t];
    for (int k = 0; k < EMB; k++) acc += sup[k] * hW1[k * 150 + t];
    float e = (acc > 0.f) ? acc : (expf(acc) - 1.f);   // elu
    val = e * hW2[t];
  }
  red[t] = val;
  __syncthreads();
  for (int off = 128; off > 0; off >>= 1) {
    if (t < off) red[t] += red[t + off];
    __syncthreads();
  }
  if (t == 0) out[g] = red[0] + hb2[0];
}

// ---------------- host ----------------

extern "C" void kernel_launch(void* const* d_in, const int* in_sizes, int n_in,
                              void* d_out, int out_size, void* d_ws, size_t ws_size,
                              hipStream_t stream) {
  const int* x      = (const int*)d_in[0];
  const int* ei     = (const int*)d_in[1];
  const int* ea     = (const int*)d_in[2];
  const int* batch  = (const int*)d_in[3];
  // d_in[4] = num_graphs (static)
  const float* atom0 = (const float*)d_in[5];
  const float* atom1 = (const float*)d_in[6];
  const float* bond0 = (const float*)d_in[7];
  const float* bond1 = (const float*)d_in[8];
  const float* W1    = (const float*)d_in[9];
  const float* b1    = (const float*)d_in[10];
  const float* W2    = (const float*)d_in[11];
  const float* b2    = (const float*)d_in[12];
  const float* gamma = (const float*)d_in[13];
  const float* beta  = (const float*)d_in[14];
  const float* hW1   = (const float*)d_in[15];
  const float* hb1   = (const float*)d_in[16];
  const float* hW2   = (const float*)d_in[17];
  const float* hb2   = (const float*)d_in[18];
  float* out = (float*)d_out;

  char* p = (char*)d_ws;
  auto carve = [&](size_t b) -> void* {
    void* r = (void*)p;
    p += (b + 255) & ~(size_t)255;
    return r;
  };
  // fixed buffers (~176 MB)
  __hip_bfloat16* agg = (__hip_bfloat16*)carve((size_t)NN * HS * 2);        // 80 MB
  __hip_bfloat16* h   = (__hip_bfloat16*)carve((size_t)NN * HS * 2);        // 80 MB
  __hip_bfloat16* W1T = (__hip_bfloat16*)carve((size_t)NLAYER * N1 * K1 * 2);
  __hip_bfloat16* W2T = (__hip_bfloat16*)carve((size_t)NLAYER * N2P * N1 * 2);
  float* b1p          = (float*)carve((size_t)NLAYER * N1 * 4);
  float* b2p          = (float*)carve((size_t)NLAYER * N2P * 4);
  float* etabg        = (float*)carve((size_t)NLAYER * 13 * HS * 4);        // 83 KB
  float* part         = (float*)carve((size_t)EMB * 2 * NRB * 4);           // 2.4 MB
  float* bnsc         = (float*)carve((size_t)NLAYER * HS * 4);
  float* bnsh         = (float*)carve((size_t)NLAYER * HS * 4);
  int* counts         = (int*)carve((size_t)NN * 4);
  int* indptr         = (int*)carve((size_t)(NN + 1) * 4);
  int* cursor         = (int*)carve((size_t)NN * 4);
  int* epacked        = (int*)carve((size_t)NE * 4);
  int* blockSums      = (int*)carve(128 * 4);
  int* blockOff       = (int*)carve(128 * 4);
  int* lastidx        = (int*)carve((size_t)NG * 4);

  size_t used = (size_t)(p - (char*)d_ws);
  size_t avail = (ws_size > used + 4096) ? (ws_size - used - 4096) : 0;
  int CHUNK = 16384;   // 20 MB — known-good floor
  if (avail >= (size_t)65536 * N1 * 2) CHUNK = 65536;         // 80 MB (R12 best-known)
  else if (avail >= (size_t)32768 * N1 * 2) CHUNK = 32768;    // 40 MB
  __hip_bfloat16* hid = (__hip_bfloat16*)carve((size_t)CHUNK * N1 * 2);

  hipMemsetAsync(counts, 0, (size_t)NN * 4, stream);

  prep_w1<<<(NLAYER * N1 * K1 + 255) / 256, 256, 0, stream>>>(W1, W1T);
  prep_w2<<<(NLAYER * N2P * N1 + 255) / 256, 256, 0, stream>>>(W2, W2T);
  prep_bias<<<(NLAYER * (N1 + N2P) + 255) / 256, 256, 0, stream>>>(b1, b2, b1p, b2p);
  prep_etab<<<(NLAYER * 13 * HS + 255) / 256, 256, 0, stream>>>(bond0, bond1, etabg);
  init_h<<<NN, 256, 0, stream>>>(x, atom0, atom1, h);

  count_edges<<<NE / 256, 256, 0, stream>>>(ei, counts);
  scan_block<<<128, 256, 0, stream>>>(counts, indptr, blockSums);
  scan_top<<<1, 128, 0, stream>>>(blockSums, blockOff);
  scan_add<<<128, 256, 0, stream>>>(indptr, blockOff);
  hipMemcpyAsync(cursor, indptr, (size_t)NN * 4, hipMemcpyDeviceToDevice, stream);
  scatter_edges<<<NE / 256, 256, 0, stream>>>(ei, ea, cursor, epacked);
  last_idx_kernel<<<NN / 256, 256, 0, stream>>>(batch, lastidx);

  for (int l = 0; l < NLAYER; l++) {
    if (l == 0)
      aggregate_kernel<0><<<NN / 64, 1024, 0, stream>>>(
          h, indptr, epacked, etabg + (size_t)l * 13 * HS, nullptr, nullptr, agg);
    else
      aggregate_kernel<1><<<NN / 64, 1024, 0, stream>>>(
          h, indptr, epacked, etabg + (size_t)l * 13 * HS,
          bnsc + (size_t)(l - 1) * HS, bnsh + (size_t)(l - 1) * HS, agg);
    for (int c0 = 0; c0 < NN; c0 += CHUNK) {
      gemm_kernel<1, 0, N1 / 128, K1, K1><<<(CHUNK / 128) * (N1 / 128), 256, 0, stream>>>(
          (const short*)(agg + (size_t)c0 * HS),
          (const short*)(W1T + (size_t)l * N1 * K1), b1p + l * N1,
          hid, nullptr, N1, N1, 0);
      gemm_kernel<0, 1, N2P / 128, N1, K2E><<<(CHUNK / 128) * (N2P / 128), 256, 0, stream>>>(
          (const short*)hid,
          (const short*)(W2T + (size_t)l * N2P * N1), b2p + l * N2P,
          h + (size_t)c0 * HS, part, HS, HS, c0 / 128);
    }
    bn_finalize<<<HS, 256, 0, stream>>>(part, gamma + (size_t)l * EMB, beta + (size_t)l * EMB,
                                        bnsc + (size_t)l * HS, bnsh + (size_t)l * HS);
  }

  head_kernel<<<NG, 256, 0, stream>>>(h, lastidx, bnsc + 4 * HS, bnsh + 4 * HS,
                                      hW1, hb1, hW2, hb2, out);
}

// Round 17
// 1649.734 us; speedup vs baseline: 1.1558x; 1.0061x over previous
//
#include <hip/hip_runtime.h>
#include <hip/hip_bf16.h>

#define NN 131072      // nodes
#define NE 262144      // edges (without self loops)
#define NG 4096        // graphs
#define EMB 300
#define HS 320         // h/agg row stride (bf16, padded, cols 300..319 == 0)
#define K1 320         // GEMM1 K
#define N1 640         // padded 600 (GEMM1 out / hid stride / GEMM2 K stride)
#define K2E 608        // GEMM2 K extent (cols 600..639 of hid are exact zeros)
#define N2P 384        // padded 300 (W2T rows; GEMM2 touches only rows 0..319)
#define NLAYER 5
#define NRB (NN / 128) // 1024 row-blocks for BN partials

typedef __attribute__((ext_vector_type(8))) short short8;
typedef __attribute__((ext_vector_type(4))) float f32x4;
typedef __attribute__((ext_vector_type(4))) unsigned short ushort4v;

__device__ __forceinline__ void gload_lds16(const void* g, void* l) {
  __builtin_amdgcn_global_load_lds((const __attribute__((address_space(1))) void*)g,
                                   (__attribute__((address_space(3))) void*)l, 16, 0, 0);
}
__device__ __forceinline__ float b2f(unsigned short u) {
  return __uint_as_float(((unsigned)u) << 16);
}
__device__ __forceinline__ unsigned short f2b(float x) {
  __hip_bfloat16 b = __float2bfloat16(x);
  return *(unsigned short*)&b;
}

// ---------------- prep kernels ----------------

__global__ void prep_w1(const float* __restrict__ W1, __hip_bfloat16* __restrict__ W1T) {
  int idx = blockIdx.x * 256 + threadIdx.x;           // 5*640*320
  if (idx >= NLAYER * N1 * K1) return;
  int l = idx / (N1 * K1); int r = idx % (N1 * K1);
  int n = r / K1; int k = r % K1;
  float v = (n < 600 && k < 300) ? W1[(size_t)(l * 300 + k) * 600 + n] : 0.f;
  W1T[idx] = __float2bfloat16(v);
}

__global__ void prep_w2(const float* __restrict__ W2, __hip_bfloat16* __restrict__ W2T) {
  int idx = blockIdx.x * 256 + threadIdx.x;           // 5*384*640
  if (idx >= NLAYER * N2P * N1) return;
  int l = idx / (N2P * N1); int r = idx % (N2P * N1);
  int n = r / N1; int k = r % N1;
  float v = (n < 300 && k < 600) ? W2[(size_t)(l * 600 + k) * 300 + n] : 0.f;
  W2T[idx] = __float2bfloat16(v);
}

__global__ void prep_bias(const float* __restrict__ b1, const float* __restrict__ b2,
                          float* __restrict__ b1p, float* __restrict__ b2p) {
  int idx = blockIdx.x * 256 + threadIdx.x;
  if (idx < NLAYER * N1) {
    int l = idx / N1, n = idx % N1;
    b1p[idx] = (n < 600) ? b1[l * 600 + n] : 0.f;
  } else {
    int k = idx - NLAYER * N1;
    if (k < NLAYER * N2P) {
      int l = k / N2P, n = k % N2P;
      b2p[k] = (n < 300) ? b2[l * 300 + n] : 0.f;
    }
  }
}

// edge-embedding tables for ALL layers: etabg[l][c][ch], c=0..12 (12 combos + self)
__global__ void prep_etab(const float* __restrict__ bond0, const float* __restrict__ bond1,
                          float* __restrict__ etabg) {
  int idx = blockIdx.x * 256 + threadIdx.x;
  if (idx >= NLAYER * 13 * HS) return;
  int l = idx / (13 * HS); int r = idx % (13 * HS);
  int c = r / HS; int ch = r % HS;
  float val = 0.f;
  if (ch < EMB) {
    int t0 = (c < 12) ? (c / 3) : 4;     // self-loop: bond type 4, dir 0
    int t1 = (c < 12) ? (c % 3) : 0;
    val = bond0[(size_t)(l * 6 + t0) * EMB + ch] + bond1[(size_t)(l * 3 + t1) * EMB + ch];
  }
  etabg[idx] = val;
}

__global__ void init_h(const int* __restrict__ x, const float* __restrict__ ae0,
                       const float* __restrict__ ae1, __hip_bfloat16* __restrict__ h) {
  int v = blockIdx.x; int t = threadIdx.x;
  int x0 = x[2 * v], x1 = x[2 * v + 1];
  for (int c = t; c < HS; c += 256)
    h[(size_t)v * HS + c] = __float2bfloat16(c < EMB ? ae0[x0 * EMB + c] + ae1[x1 * EMB + c] : 0.f);
}

// ---------------- CSR build ----------------

__global__ void count_edges(const int* __restrict__ ei, int* __restrict__ counts) {
  int j = blockIdx.x * 256 + threadIdx.x;
  if (j >= NE) return;
  atomicAdd(&counts[ei[NE + j]], 1);
}

__global__ void scan_block(const int* __restrict__ counts, int* __restrict__ indptr,
                           int* __restrict__ blockSums) {
  __shared__ int s[256];
  int b = blockIdx.x, t = threadIdx.x;
  int base = b * 1024 + t * 4;
  int4 c = *(const int4*)&counts[base];
  int tsum = c.x + c.y + c.z + c.w;
  s[t] = tsum;
  __syncthreads();
  for (int off = 1; off < 256; off <<= 1) {
    int v = (t >= off) ? s[t - off] : 0;
    __syncthreads();
    s[t] += v;
    __syncthreads();
  }
  int excl = (t == 0) ? 0 : s[t - 1];
  indptr[base + 0] = excl;
  indptr[base + 1] = excl + c.x;
  indptr[base + 2] = excl + c.x + c.y;
  indptr[base + 3] = excl + c.x + c.y + c.z;
  if (t == 255) blockSums[b] = s[255];
}

__global__ void scan_top(const int* __restrict__ blockSums, int* __restrict__ blockOff) {
  __shared__ int s[128];
  int t = threadIdx.x;
  s[t] = blockSums[t];
  __syncthreads();
  for (int off = 1; off < 128; off <<= 1) {
    int v = (t >= off) ? s[t - off] : 0;
    __syncthreads();
    s[t] += v;
    __syncthreads();
  }
  blockOff[t] = (t == 0) ? 0 : s[t - 1];
}

__global__ void scan_add(int* __restrict__ indptr, const int* __restrict__ blockOff) {
  int b = blockIdx.x, t = threadIdx.x;
  int off = blockOff[b];
  int base = b * 1024 + t * 4;
  indptr[base + 0] += off; indptr[base + 1] += off;
  indptr[base + 2] += off; indptr[base + 3] += off;
  if (b == 127 && t == 255) indptr[NN] = NE;
}

__global__ void scatter_edges(const int* __restrict__ ei, const int* __restrict__ ea,
                              int* __restrict__ cursor, int* __restrict__ epacked) {
  int j = blockIdx.x * 256 + threadIdx.x;
  if (j >= NE) return;
  int dst = ei[NE + j];
  int src = ei[j];
  int c = ea[2 * j] * 3 + ea[2 * j + 1];   // 0..11
  int pos = atomicAdd(&cursor[dst], 1);
  epacked[pos] = src | (c << 17);
}

__global__ void last_idx_kernel(const int* __restrict__ batch, int* __restrict__ lastidx) {
  int i = blockIdx.x * 256 + threadIdx.x;
  if (i >= NN) return;
  int b = batch[i];
  if (i == NN - 1 || batch[i + 1] != b) lastidx[b] = i;
}

// ---------------- aggregate (fused BN-apply + ReLU of previous layer) ----------------
// etab copied from precomputed global table; 64 nodes/block (4 per wave);
// 2-wide edge unroll (28 VGPR — R7's 4-wide cost occupancy).
template<int BN>
__global__ __launch_bounds__(1024)
void aggregate_kernel(const __hip_bfloat16* __restrict__ hg, const int* __restrict__ indptr,
                      const int* __restrict__ epacked, const float* __restrict__ etabg,
                      const float* __restrict__ bnsc, const float* __restrict__ bnsh,
                      __hip_bfloat16* __restrict__ agg) {
  __shared__ float etab[13 * HS];
  const int tid = threadIdx.x;
#pragma unroll
  for (int idx = tid; idx < 13 * HS; idx += 1024)
    etab[idx] = etabg[idx];
  __syncthreads();
  const int wid = tid >> 6, lane = tid & 63;
  const int cA = lane * 4, cB = 256 + lane;
  const unsigned short* h = (const unsigned short*)hg;

  f32x4 scA = {1.f, 1.f, 1.f, 1.f}, shA = {0.f, 0.f, 0.f, 0.f};
  float scB = 1.f, shB = 0.f;
  if (BN) {
    scA = *(const f32x4*)&bnsc[cA]; shA = *(const f32x4*)&bnsh[cA];
    scB = bnsc[cB]; shB = bnsh[cB];
  }
  auto trA = [&](float x, int k) -> float {
    if (BN) x = fmaxf(fmaf(x, scA[k], shA[k]), 0.f);
    return x;
  };
  auto trB = [&](float x) -> float {
    if (BN) x = fmaxf(fmaf(x, scB, shB), 0.f);
    return x;
  };
  const float* es = etab + 12 * HS;

  for (int it = 0; it < 4; ++it) {
    const int v = blockIdx.x * 64 + it * 16 + wid;
    const unsigned short* hv = h + (size_t)v * HS;
    ushort4v pA = *(const ushort4v*)(hv + cA);
    unsigned short pB = hv[cB];
    float a0 = trA(b2f(pA[0]), 0) + es[cA];
    float a1 = trA(b2f(pA[1]), 1) + es[cA + 1];
    float a2 = trA(b2f(pA[2]), 2) + es[cA + 2];
    float a3 = trA(b2f(pA[3]), 3) + es[cA + 3];
    float a4 = trB(b2f(pB)) + es[cB];

    const int jb = indptr[v], je = indptr[v + 1];
    int j = jb;
    for (; j + 2 <= je; j += 2) {
      int p0 = epacked[j], p1 = epacked[j + 1];
      const unsigned short* h0 = h + (size_t)(p0 & (NN - 1)) * HS;
      const unsigned short* h1 = h + (size_t)(p1 & (NN - 1)) * HS;
      ushort4v q0 = *(const ushort4v*)(h0 + cA);
      ushort4v q1 = *(const ushort4v*)(h1 + cA);
      unsigned short r0 = h0[cB], r1 = h1[cB];
      const float* e0 = etab + (p0 >> 17) * HS;
      const float* e1 = etab + (p1 >> 17) * HS;
      a0 += trA(b2f(q0[0]), 0) + e0[cA]     + trA(b2f(q1[0]), 0) + e1[cA];
      a1 += trA(b2f(q0[1]), 1) + e0[cA + 1] + trA(b2f(q1[1]), 1) + e1[cA + 1];
      a2 += trA(b2f(q0[2]), 2) + e0[cA + 2] + trA(b2f(q1[2]), 2) + e1[cA + 2];
      a3 += trA(b2f(q0[3]), 3) + e0[cA + 3] + trA(b2f(q1[3]), 3) + e1[cA + 3];
      a4 += trB(b2f(r0)) + e0[cB] + trB(b2f(r1)) + e1[cB];
    }
    if (j < je) {
      int p0 = epacked[j];
      const unsigned short* h0 = h + (size_t)(p0 & (NN - 1)) * HS;
      ushort4v q0 = *(const ushort4v*)(h0 + cA);
      unsigned short r0 = h0[cB];
      const float* e0 = etab + (p0 >> 17) * HS;
      a0 += trA(b2f(q0[0]), 0) + e0[cA];
      a1 += trA(b2f(q0[1]), 1) + e0[cA + 1];
      a2 += trA(b2f(q0[2]), 2) + e0[cA + 2];
      a3 += trA(b2f(q0[3]), 3) + e0[cA + 3];
      a4 += trB(b2f(r0)) + e0[cB];
    }

    unsigned short* av = (unsigned short*)agg + (size_t)v * HS;
    ushort4v o; o[0] = f2b(a0); o[1] = f2b(a1); o[2] = f2b(a2); o[3] = f2b(a3);
    *(ushort4v*)(av + cA) = o;
    av[cB] = f2b(a4);
  }
}

// ---------------- GEMM ----------------
// R12 skeleton, parameterized B-tile width BCOLS (128 for GEMM1; 64 for GEMM2
// so NBN=5x64=320 covers N=300 with 6% waste instead of 3x128=384 at 22%,
// and LDS drops to 36 KB -> 4 blocks/CU). 3-buffer LDS, ONE barrier per
// K-step, counted vmcnt (loads/step = 2 A + BCOLS/64 B), compile-time K,
// XOR-swizzled k-slots (dest linear per rule #21), XCD-bijective remap.
template<int RELU, int STATS, int NBN, int KSTRIDE, int KEXT, int BCOLS>
__global__ __launch_bounds__(256)
void gemm_kernel(const short* __restrict__ A, const short* __restrict__ BT,
                 const float* __restrict__ bias, __hip_bfloat16* __restrict__ Cout,
                 float* __restrict__ part, int outStride, int outBound, int rbBase) {
  constexpr int BSH = BCOLS * 32;          // B shorts per buffer
  constexpr int BUFSZ = 4096 + BSH;        // shorts per buffer (A 128x32 + B)
  constexpr int WCOL = BCOLS / 2;          // cols per wave
  constexpr int NF = WCOL / 16;            // col fragments per wave
  __shared__ short smem[3 * BUFSZ];
  __shared__ float sred[STATS ? BCOLS : 1][2];
  const int tid = threadIdx.x;
  const int wid = tid >> 6, lane = tid & 63;
  const int wm = wid >> 1, wn = wid & 1;
  f32x4 acc[4][NF] = {};

  // XCD-bijective remap (gridDim.x % 8 == 0 in all launch configs)
  const int cpx = gridDim.x >> 3;
  const int logical = (blockIdx.x & 7) * cpx + (blockIdx.x >> 3);
  const int bn = logical % NBN;
  const int bm = logical / NBN;

  const short* Ag = A + (size_t)bm * 128 * KSTRIDE;
  const short* Bg = BT + (size_t)bn * BCOLS * KSTRIDE;
  const int r2 = tid >> 2;                                   // staged row 0..63
  const int ksw = ((tid & 3) ^ ((tid >> 3) & 3)) * 8;        // swizzled k-src (shorts)
  const int arow_h = lane & 15;                              // read row within 16
  const int koffR = (((lane >> 4) ^ ((arow_h >> 1) & 3)) * 8);  // swizzled k-read (shorts)

  const short* Ao = Ag + (size_t)r2 * KSTRIDE + ksw;
  const short* Bo = Bg + (size_t)r2 * KSTRIDE + ksw;

  auto stage = [&](int buf, int kt) {
    short* s = smem + buf * BUFSZ;
    gload_lds16(Ao + kt,                 s + tid * 8);
    gload_lds16(Ao + kt + 64 * KSTRIDE,  s + 2048 + tid * 8);
    gload_lds16(Bo + kt,                 s + 4096 + tid * 8);
    if (BCOLS == 128)
      gload_lds16(Bo + kt + 64 * KSTRIDE, s + 6144 + tid * 8);
  };

  constexpr int NT = KEXT / 32;
  stage(0, 0);
  stage(1, 32);
#pragma unroll
  for (int t = 0; t < NT; ++t) {
    if (t + 1 < NT) {
      if (BCOLS == 128) asm volatile("s_waitcnt vmcnt(4)" ::: "memory");
      else              asm volatile("s_waitcnt vmcnt(3)" ::: "memory");
    } else {
      asm volatile("s_waitcnt vmcnt(0)" ::: "memory");
    }
    __builtin_amdgcn_sched_barrier(0);
    __builtin_amdgcn_s_barrier();
    const int rb = t % 3;
    if (t + 2 < NT) stage((t + 2) % 3, (t + 2) * 32);
    const short* sA = smem + rb * BUFSZ + wm * 2048;
    const short* sB = smem + rb * BUFSZ + 4096 + wn * (WCOL * 32);
    short8 af[4], bf[NF];
#pragma unroll
    for (int i = 0; i < 4; i++) af[i] = *(const short8*)&sA[(arow_h + i * 16) * 32 + koffR];
#pragma unroll
    for (int j = 0; j < NF; j++) bf[j] = *(const short8*)&sB[(arow_h + j * 16) * 32 + koffR];
#pragma unroll
    for (int i = 0; i < 4; i++)
#pragma unroll
      for (int j = 0; j < NF; j++)
        acc[i][j] = __builtin_amdgcn_mfma_f32_16x16x32_bf16(af[i], bf[j], acc[i][j], 0, 0, 0);
    __builtin_amdgcn_sched_barrier(0);
  }

  const int row0 = bm * 128 + wm * 64 + (lane >> 4) * 4;
  const int col0 = bn * BCOLS + wn * WCOL + (lane & 15);
  float bs[NF];
#pragma unroll
  for (int j = 0; j < NF; j++) bs[j] = bias[col0 + j * 16];
  float ssum[NF], ssq[NF];
#pragma unroll
  for (int j = 0; j < NF; j++) { ssum[j] = 0.f; ssq[j] = 0.f; }
  if (STATS) {
    if (tid < BCOLS) { sred[tid][0] = 0.f; sred[tid][1] = 0.f; }
    __syncthreads();
  }
#pragma unroll
  for (int i = 0; i < 4; i++) {
#pragma unroll
    for (int p = 0; p < 4; p++) {
      const size_t row = row0 + i * 16 + p;
#pragma unroll
      for (int j = 0; j < NF; j++) {
        const int col = col0 + j * 16;
        float v = acc[i][j][p] + bs[j];
        if (STATS) { ssum[j] += v; ssq[j] += v * v; }
        if (RELU) v = fmaxf(v, 0.f);
        if (col < outBound)
          Cout[row * (size_t)outStride + col] = __float2bfloat16(v);
      }
    }
  }
  if (STATS) {
#pragma unroll
    for (int j = 0; j < NF; j++) {
      const int cw = wn * WCOL + j * 16 + (lane & 15);
      atomicAdd(&sred[cw][0], ssum[j]);
      atomicAdd(&sred[cw][1], ssq[j]);
    }
    __syncthreads();
    if (tid < BCOLS) {
      const int col = bn * BCOLS + tid;
      if (col < EMB) {
        const int rb2 = rbBase + bm;
        part[(size_t)col * (2 * NRB) + rb2] = sred[tid][0];
        part[(size_t)col * (2 * NRB) + NRB + rb2] = sred[tid][1];
      }
    }
  }
}

// ---------------- BN finalize: partials -> scale/shift ----------------
__global__ __launch_bounds__(256)
void bn_finalize(const float* __restrict__ part, const float* __restrict__ gamma,
                 const float* __restrict__ beta, float* __restrict__ bnsc,
                 float* __restrict__ bnsh) {
  __shared__ float rs[256], rq[256];
  const int c = blockIdx.x, t = threadIdx.x;
  if (c >= EMB) {
    if (t == 0) { bnsc[c] = 0.f; bnsh[c] = 0.f; }
    return;
  }
  float s = 0.f, q = 0.f;
  for (int rb = t; rb < NRB; rb += 256) {
    s += part[(size_t)c * (2 * NRB) + rb];
    q += part[(size_t)c * (2 * NRB) + NRB + rb];
  }
  rs[t] = s; rq[t] = q;
  __syncthreads();
  for (int off = 128; off > 0; off >>= 1) {
    if (t < off) { rs[t] += rs[t + off]; rq[t] += rq[t + off]; }
    __syncthreads();
  }
  if (t == 0) {
    float mean = rs[0] / (float)NN;
    float var = rq[0] / (float)NN - mean * mean;
    float sc = rsqrtf(var + 1e-5f) * gamma[c];
    bnsc[c] = sc;
    bnsh[c] = beta[c] - mean * sc;
  }
}

// ---------------- head (applies final BN, no relu) ----------------
__global__ __launch_bounds__(256)
void head_kernel(const __hip_bfloat16* __restrict__ h, const int* __restrict__ lastidx,
                 const float* __restrict__ bnsc4, const float* __restrict__ bnsh4,
                 const float* __restrict__ hW1, const float* __restrict__ hb1,
                 const float* __restrict__ hW2, const float* __restrict__ hb2,
                 float* __restrict__ out) {
  __shared__ float sup[EMB];
  __shared__ float red[256];
  int g = blockIdx.x, t = threadIdx.x;
  int v = lastidx[g];
  for (int c = t; c < EMB; c += 256)
    sup[c] = b2f(((const unsigned short*)h)[(size_t)v * HS + c]) * bnsc4[c] + bnsh4[c];
  __syncthreads();
  float val = 0.f;
  if (t < 150) {
    float acc = hb1[t];
    for (int k = 0; k < EMB; k++) acc += sup[k] * hW1[k * 150 + t];
    float e = (acc > 0.f) ? acc : (expf(acc) - 1.f);   // elu
    val = e * hW2[t];
  }
  red[t] = val;
  __syncthreads();
  for (int off = 128; off > 0; off >>= 1) {
    if (t < off) red[t] += red[t + off];
    __syncthreads();
  }
  if (t == 0) out[g] = red[0] + hb2[0];
}

// ---------------- host ----------------

extern "C" void kernel_launch(void* const* d_in, const int* in_sizes, int n_in,
                              void* d_out, int out_size, void* d_ws, size_t ws_size,
                              hipStream_t stream) {
  const int* x      = (const int*)d_in[0];
  const int* ei     = (const int*)d_in[1];
  const int* ea     = (const int*)d_in[2];
  const int* batch  = (const int*)d_in[3];
  // d_in[4] = num_graphs (static)
  const float* atom0 = (const float*)d_in[5];
  const float* atom1 = (const float*)d_in[6];
  const float* bond0 = (const float*)d_in[7];
  const float* bond1 = (const float*)d_in[8];
  const float* W1    = (const float*)d_in[9];
  const float* b1    = (const float*)d_in[10];
  const float* W2    = (const float*)d_in[11];
  const float* b2    = (const float*)d_in[12];
  const float* gamma = (const float*)d_in[13];
  const float* beta  = (const float*)d_in[14];
  const float* hW1   = (const float*)d_in[15];
  const float* hb1   = (const float*)d_in[16];
  const float* hW2   = (const float*)d_in[17];
  const float* hb2   = (const float*)d_in[18];
  float* out = (float*)d_out;

  char* p = (char*)d_ws;
  auto carve = [&](size_t b) -> void* {
    void* r = (void*)p;
    p += (b + 255) & ~(size_t)255;
    return r;
  };
  // fixed buffers (~176 MB)
  __hip_bfloat16* agg = (__hip_bfloat16*)carve((size_t)NN * HS * 2);        // 80 MB
  __hip_bfloat16* h   = (__hip_bfloat16*)carve((size_t)NN * HS * 2);        // 80 MB
  __hip_bfloat16* W1T = (__hip_bfloat16*)carve((size_t)NLAYER * N1 * K1 * 2);
  __hip_bfloat16* W2T = (__hip_bfloat16*)carve((size_t)NLAYER * N2P * N1 * 2);
  float* b1p          = (float*)carve((size_t)NLAYER * N1 * 4);
  float* b2p          = (float*)carve((size_t)NLAYER * N2P * 4);
  float* etabg        = (float*)carve((size_t)NLAYER * 13 * HS * 4);        // 83 KB
  float* part         = (float*)carve((size_t)EMB * 2 * NRB * 4);           // 2.4 MB
  float* bnsc         = (float*)carve((size_t)NLAYER * HS * 4);
  float* bnsh         = (float*)carve((size_t)NLAYER * HS * 4);
  int* counts         = (int*)carve((size_t)NN * 4);
  int* indptr         = (int*)carve((size_t)(NN + 1) * 4);
  int* cursor         = (int*)carve((size_t)NN * 4);
  int* epacked        = (int*)carve((size_t)NE * 4);
  int* blockSums      = (int*)carve(128 * 4);
  int* blockOff       = (int*)carve(128 * 4);
  int* lastidx        = (int*)carve((size_t)NG * 4);

  size_t used = (size_t)(p - (char*)d_ws);
  size_t avail = (ws_size > used + 4096) ? (ws_size - used - 4096) : 0;
  int CHUNK = 16384;   // 20 MB — known-good floor
  if (avail >= (size_t)65536 * N1 * 2) CHUNK = 65536;         // 80 MB (R12 best-known)
  else if (avail >= (size_t)32768 * N1 * 2) CHUNK = 32768;    // 40 MB
  __hip_bfloat16* hid = (__hip_bfloat16*)carve((size_t)CHUNK * N1 * 2);

  hipMemsetAsync(counts, 0, (size_t)NN * 4, stream);

  prep_w1<<<(NLAYER * N1 * K1 + 255) / 256, 256, 0, stream>>>(W1, W1T);
  prep_w2<<<(NLAYER * N2P * N1 + 255) / 256, 256, 0, stream>>>(W2, W2T);
  prep_bias<<<(NLAYER * (N1 + N2P) + 255) / 256, 256, 0, stream>>>(b1, b2, b1p, b2p);
  prep_etab<<<(NLAYER * 13 * HS + 255) / 256, 256, 0, stream>>>(bond0, bond1, etabg);
  init_h<<<NN, 256, 0, stream>>>(x, atom0, atom1, h);

  count_edges<<<NE / 256, 256, 0, stream>>>(ei, counts);
  scan_block<<<128, 256, 0, stream>>>(counts, indptr, blockSums);
  scan_top<<<1, 128, 0, stream>>>(blockSums, blockOff);
  scan_add<<<128, 256, 0, stream>>>(indptr, blockOff);
  hipMemcpyAsync(cursor, indptr, (size_t)NN * 4, hipMemcpyDeviceToDevice, stream);
  scatter_edges<<<NE / 256, 256, 0, stream>>>(ei, ea, cursor, epacked);
  last_idx_kernel<<<NN / 256, 256, 0, stream>>>(batch, lastidx);

  for (int l = 0; l < NLAYER; l++) {
    if (l == 0)
      aggregate_kernel<0><<<NN / 64, 1024, 0, stream>>>(
          h, indptr, epacked, etabg + (size_t)l * 13 * HS, nullptr, nullptr, agg);
    else
      aggregate_kernel<1><<<NN / 64, 1024, 0, stream>>>(
          h, indptr, epacked, etabg + (size_t)l * 13 * HS,
          bnsc + (size_t)(l - 1) * HS, bnsh + (size_t)(l - 1) * HS, agg);
    for (int c0 = 0; c0 < NN; c0 += CHUNK) {
      gemm_kernel<1, 0, N1 / 128, K1, K1, 128><<<(CHUNK / 128) * (N1 / 128), 256, 0, stream>>>(
          (const short*)(agg + (size_t)c0 * HS),
          (const short*)(W1T + (size_t)l * N1 * K1), b1p + l * N1,
          hid, nullptr, N1, N1, 0);
      gemm_kernel<0, 1, 5, N1, K2E, 64><<<(CHUNK / 128) * 5, 256, 0, stream>>>(
          (const short*)hid,
          (const short*)(W2T + (size_t)l * N2P * N1), b2p + l * N2P,
          h + (size_t)c0 * HS, part, HS, HS, c0 / 128);
    }
    bn_finalize<<<HS, 256, 0, stream>>>(part, gamma + (size_t)l * EMB, beta + (size_t)l * EMB,
                                        bnsc + (size_t)l * HS, bnsh + (size_t)l * HS);
  }

  head_kernel<<<NG, 256, 0, stream>>>(h, lastidx, bnsc + 4 * HS, bnsh + 4 * HS,
                                      hW1, hb1, hW2, hb2, out);
}

// Round 18
// 1582.578 us; speedup vs baseline: 1.2048x; 1.0424x over previous
//
#include <hip/hip_runtime.h>
#include <hip/hip_bf16.h>

#define NN 131072      // nodes
#define NE 262144      // edges (without self loops)
#define NG 4096        // graphs
#define EMB 300
#define HS 320         // h/agg row stride (bf16, padded, cols 300..319 == 0)
#define K1 320         // GEMM1 K
#define N1 640         // padded 600 (GEMM1 out / hid stride / GEMM2 K stride)
#define K2E 608        // GEMM2 K extent (cols 600..639 of hid are exact zeros)
#define N2P 384        // padded 300 (W2T rows; GEMM2 touches only rows 0..319)
#define NLAYER 5
#define NRB (NN / 128) // 1024 row-blocks for BN partials

typedef __attribute__((ext_vector_type(8))) short short8;
typedef __attribute__((ext_vector_type(4))) float f32x4;
typedef __attribute__((ext_vector_type(4))) unsigned short ushort4v;

__device__ __forceinline__ void gload_lds16(const void* g, void* l) {
  __builtin_amdgcn_global_load_lds((const __attribute__((address_space(1))) void*)g,
                                   (__attribute__((address_space(3))) void*)l, 16, 0, 0);
}
__device__ __forceinline__ float b2f(unsigned short u) {
  return __uint_as_float(((unsigned)u) << 16);
}
__device__ __forceinline__ unsigned short f2b(float x) {
  __hip_bfloat16 b = __float2bfloat16(x);
  return *(unsigned short*)&b;
}

// ---------------- prep kernels ----------------

__global__ void prep_w1(const float* __restrict__ W1, __hip_bfloat16* __restrict__ W1T) {
  int idx = blockIdx.x * 256 + threadIdx.x;           // 5*640*320
  if (idx >= NLAYER * N1 * K1) return;
  int l = idx / (N1 * K1); int r = idx % (N1 * K1);
  int n = r / K1; int k = r % K1;
  float v = (n < 600 && k < 300) ? W1[(size_t)(l * 300 + k) * 600 + n] : 0.f;
  W1T[idx] = __float2bfloat16(v);
}

__global__ void prep_w2(const float* __restrict__ W2, __hip_bfloat16* __restrict__ W2T) {
  int idx = blockIdx.x * 256 + threadIdx.x;           // 5*384*640
  if (idx >= NLAYER * N2P * N1) return;
  int l = idx / (N2P * N1); int r = idx % (N2P * N1);
  int n = r / N1; int k = r % N1;
  float v = (n < 300 && k < 600) ? W2[(size_t)(l * 600 + k) * 300 + n] : 0.f;
  W2T[idx] = __float2bfloat16(v);
}

__global__ void prep_bias(const float* __restrict__ b1, const float* __restrict__ b2,
                          float* __restrict__ b1p, float* __restrict__ b2p) {
  int idx = blockIdx.x * 256 + threadIdx.x;
  if (idx < NLAYER * N1) {
    int l = idx / N1, n = idx % N1;
    b1p[idx] = (n < 600) ? b1[l * 600 + n] : 0.f;
  } else {
    int k = idx - NLAYER * N1;
    if (k < NLAYER * N2P) {
      int l = k / N2P, n = k % N2P;
      b2p[k] = (n < 300) ? b2[l * 300 + n] : 0.f;
    }
  }
}

// edge-embedding tables for ALL layers: etabg[l][c][ch], c=0..12 (12 combos + self)
__global__ void prep_etab(const float* __restrict__ bond0, const float* __restrict__ bond1,
                          float* __restrict__ etabg) {
  int idx = blockIdx.x * 256 + threadIdx.x;
  if (idx >= NLAYER * 13 * HS) return;
  int l = idx / (13 * HS); int r = idx % (13 * HS);
  int c = r / HS; int ch = r % HS;
  float val = 0.f;
  if (ch < EMB) {
    int t0 = (c < 12) ? (c / 3) : 4;     // self-loop: bond type 4, dir 0
    int t1 = (c < 12) ? (c % 3) : 0;
    val = bond0[(size_t)(l * 6 + t0) * EMB + ch] + bond1[(size_t)(l * 3 + t1) * EMB + ch];
  }
  etabg[idx] = val;
}

__global__ void init_h(const int* __restrict__ x, const float* __restrict__ ae0,
                       const float* __restrict__ ae1, __hip_bfloat16* __restrict__ h) {
  int v = blockIdx.x; int t = threadIdx.x;
  int x0 = x[2 * v], x1 = x[2 * v + 1];
  for (int c = t; c < HS; c += 256)
    h[(size_t)v * HS + c] = __float2bfloat16(c < EMB ? ae0[x0 * EMB + c] + ae1[x1 * EMB + c] : 0.f);
}

// ---------------- CSR build ----------------

__global__ void count_edges(const int* __restrict__ ei, int* __restrict__ counts) {
  int j = blockIdx.x * 256 + threadIdx.x;
  if (j >= NE) return;
  atomicAdd(&counts[ei[NE + j]], 1);
}

__global__ void scan_block(const int* __restrict__ counts, int* __restrict__ indptr,
                           int* __restrict__ blockSums) {
  __shared__ int s[256];
  int b = blockIdx.x, t = threadIdx.x;
  int base = b * 1024 + t * 4;
  int4 c = *(const int4*)&counts[base];
  int tsum = c.x + c.y + c.z + c.w;
  s[t] = tsum;
  __syncthreads();
  for (int off = 1; off < 256; off <<= 1) {
    int v = (t >= off) ? s[t - off] : 0;
    __syncthreads();
    s[t] += v;
    __syncthreads();
  }
  int excl = (t == 0) ? 0 : s[t - 1];
  indptr[base + 0] = excl;
  indptr[base + 1] = excl + c.x;
  indptr[base + 2] = excl + c.x + c.y;
  indptr[base + 3] = excl + c.x + c.y + c.z;
  if (t == 255) blockSums[b] = s[255];
}

__global__ void scan_top(const int* __restrict__ blockSums, int* __restrict__ blockOff) {
  __shared__ int s[128];
  int t = threadIdx.x;
  s[t] = blockSums[t];
  __syncthreads();
  for (int off = 1; off < 128; off <<= 1) {
    int v = (t >= off) ? s[t - off] : 0;
    __syncthreads();
    s[t] += v;
    __syncthreads();
  }
  blockOff[t] = (t == 0) ? 0 : s[t - 1];
}

__global__ void scan_add(int* __restrict__ indptr, const int* __restrict__ blockOff) {
  int b = blockIdx.x, t = threadIdx.x;
  int off = blockOff[b];
  int base = b * 1024 + t * 4;
  indptr[base + 0] += off; indptr[base + 1] += off;
  indptr[base + 2] += off; indptr[base + 3] += off;
  if (b == 127 && t == 255) indptr[NN] = NE;
}

__global__ void scatter_edges(const int* __restrict__ ei, const int* __restrict__ ea,
                              int* __restrict__ cursor, int* __restrict__ epacked) {
  int j = blockIdx.x * 256 + threadIdx.x;
  if (j >= NE) return;
  int dst = ei[NE + j];
  int src = ei[j];
  int c = ea[2 * j] * 3 + ea[2 * j + 1];   // 0..11
  int pos = atomicAdd(&cursor[dst], 1);
  epacked[pos] = src | (c << 17);
}

__global__ void last_idx_kernel(const int* __restrict__ batch, int* __restrict__ lastidx) {
  int i = blockIdx.x * 256 + threadIdx.x;
  if (i >= NN) return;
  int b = batch[i];
  if (i == NN - 1 || batch[i + 1] != b) lastidx[b] = i;
}

// ---------------- aggregate (fused BN-apply + ReLU of previous layer) ----------------
// etab copied from precomputed global table; 64 nodes/block (4 per wave);
// 2-wide edge unroll (28 VGPR — R7's 4-wide cost occupancy).
template<int BN>
__global__ __launch_bounds__(1024)
void aggregate_kernel(const __hip_bfloat16* __restrict__ hg, const int* __restrict__ indptr,
                      const int* __restrict__ epacked, const float* __restrict__ etabg,
                      const float* __restrict__ bnsc, const float* __restrict__ bnsh,
                      __hip_bfloat16* __restrict__ agg) {
  __shared__ float etab[13 * HS];
  const int tid = threadIdx.x;
#pragma unroll
  for (int idx = tid; idx < 13 * HS; idx += 1024)
    etab[idx] = etabg[idx];
  __syncthreads();
  const int wid = tid >> 6, lane = tid & 63;
  const int cA = lane * 4, cB = 256 + lane;
  const unsigned short* h = (const unsigned short*)hg;

  f32x4 scA = {1.f, 1.f, 1.f, 1.f}, shA = {0.f, 0.f, 0.f, 0.f};
  float scB = 1.f, shB = 0.f;
  if (BN) {
    scA = *(const f32x4*)&bnsc[cA]; shA = *(const f32x4*)&bnsh[cA];
    scB = bnsc[cB]; shB = bnsh[cB];
  }
  auto trA = [&](float x, int k) -> float {
    if (BN) x = fmaxf(fmaf(x, scA[k], shA[k]), 0.f);
    return x;
  };
  auto trB = [&](float x) -> float {
    if (BN) x = fmaxf(fmaf(x, scB, shB), 0.f);
    return x;
  };
  const float* es = etab + 12 * HS;

  for (int it = 0; it < 4; ++it) {
    const int v = blockIdx.x * 64 + it * 16 + wid;
    const unsigned short* hv = h + (size_t)v * HS;
    ushort4v pA = *(const ushort4v*)(hv + cA);
    unsigned short pB = hv[cB];
    float a0 = trA(b2f(pA[0]), 0) + es[cA];
    float a1 = trA(b2f(pA[1]), 1) + es[cA + 1];
    float a2 = trA(b2f(pA[2]), 2) + es[cA + 2];
    float a3 = trA(b2f(pA[3]), 3) + es[cA + 3];
    float a4 = trB(b2f(pB)) + es[cB];

    const int jb = indptr[v], je = indptr[v + 1];
    int j = jb;
    for (; j + 2 <= je; j += 2) {
      int p0 = epacked[j], p1 = epacked[j + 1];
      const unsigned short* h0 = h + (size_t)(p0 & (NN - 1)) * HS;
      const unsigned short* h1 = h + (size_t)(p1 & (NN - 1)) * HS;
      ushort4v q0 = *(const ushort4v*)(h0 + cA);
      ushort4v q1 = *(const ushort4v*)(h1 + cA);
      unsigned short r0 = h0[cB], r1 = h1[cB];
      const float* e0 = etab + (p0 >> 17) * HS;
      const float* e1 = etab + (p1 >> 17) * HS;
      a0 += trA(b2f(q0[0]), 0) + e0[cA]     + trA(b2f(q1[0]), 0) + e1[cA];
      a1 += trA(b2f(q0[1]), 1) + e0[cA + 1] + trA(b2f(q1[1]), 1) + e1[cA + 1];
      a2 += trA(b2f(q0[2]), 2) + e0[cA + 2] + trA(b2f(q1[2]), 2) + e1[cA + 2];
      a3 += trA(b2f(q0[3]), 3) + e0[cA + 3] + trA(b2f(q1[3]), 3) + e1[cA + 3];
      a4 += trB(b2f(r0)) + e0[cB] + trB(b2f(r1)) + e1[cB];
    }
    if (j < je) {
      int p0 = epacked[j];
      const unsigned short* h0 = h + (size_t)(p0 & (NN - 1)) * HS;
      ushort4v q0 = *(const ushort4v*)(h0 + cA);
      unsigned short r0 = h0[cB];
      const float* e0 = etab + (p0 >> 17) * HS;
      a0 += trA(b2f(q0[0]), 0) + e0[cA];
      a1 += trA(b2f(q0[1]), 1) + e0[cA + 1];
      a2 += trA(b2f(q0[2]), 2) + e0[cA + 2];
      a3 += trA(b2f(q0[3]), 3) + e0[cA + 3];
      a4 += trB(b2f(r0)) + e0[cB];
    }

    unsigned short* av = (unsigned short*)agg + (size_t)v * HS;
    ushort4v o; o[0] = f2b(a0); o[1] = f2b(a1); o[2] = f2b(a2); o[3] = f2b(a3);
    *(ushort4v*)(av + cA) = o;
    av[cB] = f2b(a4);
  }
}

// ---------------- GEMM ----------------
// R12 skeleton, 64-col B tiles for BOTH GEMMs now: BUFSZ 12 KB, 3-buf = 36 KB
// -> 4 blocks/CU (16 waves, up from 12); acc halves -> ~52 VGPR. R13 showed
// waves/CU dominates per-wave work at this latency-bound point; this is the
// symmetric (favorable) corner. GEMM1 NBN=10 (640), GEMM2 NBN=5 (320, 6% pad).
// 3-buffer LDS, ONE barrier per K-step, counted vmcnt(3), compile-time K,
// XOR-swizzled k-slots (dest linear per rule #21), XCD-bijective remap.
template<int RELU, int STATS, int NBN, int KSTRIDE, int KEXT, int BCOLS>
__global__ __launch_bounds__(256)
void gemm_kernel(const short* __restrict__ A, const short* __restrict__ BT,
                 const float* __restrict__ bias, __hip_bfloat16* __restrict__ Cout,
                 float* __restrict__ part, int outStride, int outBound, int rbBase) {
  constexpr int BSH = BCOLS * 32;          // B shorts per buffer
  constexpr int BUFSZ = 4096 + BSH;        // shorts per buffer (A 128x32 + B)
  constexpr int WCOL = BCOLS / 2;          // cols per wave
  constexpr int NF = WCOL / 16;            // col fragments per wave
  __shared__ short smem[3 * BUFSZ];
  __shared__ float sred[STATS ? BCOLS : 1][2];
  const int tid = threadIdx.x;
  const int wid = tid >> 6, lane = tid & 63;
  const int wm = wid >> 1, wn = wid & 1;
  f32x4 acc[4][NF] = {};

  // XCD-bijective remap (gridDim.x % 8 == 0 in all launch configs)
  const int cpx = gridDim.x >> 3;
  const int logical = (blockIdx.x & 7) * cpx + (blockIdx.x >> 3);
  const int bn = logical % NBN;
  const int bm = logical / NBN;

  const short* Ag = A + (size_t)bm * 128 * KSTRIDE;
  const short* Bg = BT + (size_t)bn * BCOLS * KSTRIDE;
  const int r2 = tid >> 2;                                   // staged row 0..63
  const int ksw = ((tid & 3) ^ ((tid >> 3) & 3)) * 8;        // swizzled k-src (shorts)
  const int arow_h = lane & 15;                              // read row within 16
  const int koffR = (((lane >> 4) ^ ((arow_h >> 1) & 3)) * 8);  // swizzled k-read (shorts)

  const short* Ao = Ag + (size_t)r2 * KSTRIDE + ksw;
  const short* Bo = Bg + (size_t)r2 * KSTRIDE + ksw;

  auto stage = [&](int buf, int kt) {
    short* s = smem + buf * BUFSZ;
    gload_lds16(Ao + kt,                 s + tid * 8);
    gload_lds16(Ao + kt + 64 * KSTRIDE,  s + 2048 + tid * 8);
    gload_lds16(Bo + kt,                 s + 4096 + tid * 8);
    if (BCOLS == 128)
      gload_lds16(Bo + kt + 64 * KSTRIDE, s + 6144 + tid * 8);
  };

  constexpr int NT = KEXT / 32;
  stage(0, 0);
  stage(1, 32);
#pragma unroll
  for (int t = 0; t < NT; ++t) {
    if (t + 1 < NT) {
      if (BCOLS == 128) asm volatile("s_waitcnt vmcnt(4)" ::: "memory");
      else              asm volatile("s_waitcnt vmcnt(3)" ::: "memory");
    } else {
      asm volatile("s_waitcnt vmcnt(0)" ::: "memory");
    }
    __builtin_amdgcn_sched_barrier(0);
    __builtin_amdgcn_s_barrier();
    const int rb = t % 3;
    if (t + 2 < NT) stage((t + 2) % 3, (t + 2) * 32);
    const short* sA = smem + rb * BUFSZ + wm * 2048;
    const short* sB = smem + rb * BUFSZ + 4096 + wn * (WCOL * 32);
    short8 af[4], bf[NF];
#pragma unroll
    for (int i = 0; i < 4; i++) af[i] = *(const short8*)&sA[(arow_h + i * 16) * 32 + koffR];
#pragma unroll
    for (int j = 0; j < NF; j++) bf[j] = *(const short8*)&sB[(arow_h + j * 16) * 32 + koffR];
#pragma unroll
    for (int i = 0; i < 4; i++)
#pragma unroll
      for (int j = 0; j < NF; j++)
        acc[i][j] = __builtin_amdgcn_mfma_f32_16x16x32_bf16(af[i], bf[j], acc[i][j], 0, 0, 0);
    __builtin_amdgcn_sched_barrier(0);
  }

  const int row0 = bm * 128 + wm * 64 + (lane >> 4) * 4;
  const int col0 = bn * BCOLS + wn * WCOL + (lane & 15);
  float bs[NF];
#pragma unroll
  for (int j = 0; j < NF; j++) bs[j] = bias[col0 + j * 16];
  float ssum[NF], ssq[NF];
#pragma unroll
  for (int j = 0; j < NF; j++) { ssum[j] = 0.f; ssq[j] = 0.f; }
  if (STATS) {
    if (tid < BCOLS) { sred[tid][0] = 0.f; sred[tid][1] = 0.f; }
    __syncthreads();
  }
#pragma unroll
  for (int i = 0; i < 4; i++) {
#pragma unroll
    for (int p = 0; p < 4; p++) {
      const size_t row = row0 + i * 16 + p;
#pragma unroll
      for (int j = 0; j < NF; j++) {
        const int col = col0 + j * 16;
        float v = acc[i][j][p] + bs[j];
        if (STATS) { ssum[j] += v; ssq[j] += v * v; }
        if (RELU) v = fmaxf(v, 0.f);
        if (col < outBound)
          Cout[row * (size_t)outStride + col] = __float2bfloat16(v);
      }
    }
  }
  if (STATS) {
#pragma unroll
    for (int j = 0; j < NF; j++) {
      const int cw = wn * WCOL + j * 16 + (lane & 15);
      atomicAdd(&sred[cw][0], ssum[j]);
      atomicAdd(&sred[cw][1], ssq[j]);
    }
    __syncthreads();
    if (tid < BCOLS) {
      const int col = bn * BCOLS + tid;
      if (col < EMB) {
        const int rb2 = rbBase + bm;
        part[(size_t)col * (2 * NRB) + rb2] = sred[tid][0];
        part[(size_t)col * (2 * NRB) + NRB + rb2] = sred[tid][1];
      }
    }
  }
}

// ---------------- BN finalize: partials -> scale/shift ----------------
__global__ __launch_bounds__(256)
void bn_finalize(const float* __restrict__ part, const float* __restrict__ gamma,
                 const float* __restrict__ beta, float* __restrict__ bnsc,
                 float* __restrict__ bnsh) {
  __shared__ float rs[256], rq[256];
  const int c = blockIdx.x, t = threadIdx.x;
  if (c >= EMB) {
    if (t == 0) { bnsc[c] = 0.f; bnsh[c] = 0.f; }
    return;
  }
  float s = 0.f, q = 0.f;
  for (int rb = t; rb < NRB; rb += 256) {
    s += part[(size_t)c * (2 * NRB) + rb];
    q += part[(size_t)c * (2 * NRB) + NRB + rb];
  }
  rs[t] = s; rq[t] = q;
  __syncthreads();
  for (int off = 128; off > 0; off >>= 1) {
    if (t < off) { rs[t] += rs[t + off]; rq[t] += rq[t + off]; }
    __syncthreads();
  }
  if (t == 0) {
    float mean = rs[0] / (float)NN;
    float var = rq[0] / (float)NN - mean * mean;
    float sc = rsqrtf(var + 1e-5f) * gamma[c];
    bnsc[c] = sc;
    bnsh[c] = beta[c] - mean * sc;
  }
}

// ---------------- head (applies final BN, no relu) ----------------
__global__ __launch_bounds__(256)
void head_kernel(const __hip_bfloat16* __restrict__ h, const int* __restrict__ lastidx,
                 const float* __restrict__ bnsc4, const float* __restrict__ bnsh4,
                 const float* __restrict__ hW1, const float* __restrict__ hb1,
                 const float* __restrict__ hW2, const float* __restrict__ hb2,
                 float* __restrict__ out) {
  __shared__ float sup[EMB];
  __shared__ float red[256];
  int g = blockIdx.x, t = threadIdx.x;
  int v = lastidx[g];
  for (int c = t; c < EMB; c += 256)
    sup[c] = b2f(((const unsigned short*)h)[(size_t)v * HS + c]) * bnsc4[c] + bnsh4[c];
  __syncthreads();
  float val = 0.f;
  if (t < 150) {
    float acc = hb1[t];
    for (int k = 0; k < EMB; k++) acc += sup[k] * hW1[k * 150 + t];
    float e = (acc > 0.f) ? acc : (expf(acc) - 1.f);   // elu
    val = e * hW2[t];
  }
  red[t] = val;
  __syncthreads();
  for (int off = 128; off > 0; off >>= 1) {
    if (t < off) red[t] += red[t + off];
    __syncthreads();
  }
  if (t == 0) out[g] = red[0] + hb2[0];
}

// ---------------- host ----------------

extern "C" void kernel_launch(void* const* d_in, const int* in_sizes, int n_in,
                              void* d_out, int out_size, void* d_ws, size_t ws_size,
                              hipStream_t stream) {
  const int* x      = (const int*)d_in[0];
  const int* ei     = (const int*)d_in[1];
  const int* ea     = (const int*)d_in[2];
  const int* batch  = (const int*)d_in[3];
  // d_in[4] = num_graphs (static)
  const float* atom0 = (const float*)d_in[5];
  const float* atom1 = (const float*)d_in[6];
  const float* bond0 = (const float*)d_in[7];
  const float* bond1 = (const float*)d_in[8];
  const float* W1    = (const float*)d_in[9];
  const float* b1    = (const float*)d_in[10];
  const float* W2    = (const float*)d_in[11];
  const float* b2    = (const float*)d_in[12];
  const float* gamma = (const float*)d_in[13];
  const float* beta  = (const float*)d_in[14];
  const float* hW1   = (const float*)d_in[15];
  const float* hb1   = (const float*)d_in[16];
  const float* hW2   = (const float*)d_in[17];
  const float* hb2   = (const float*)d_in[18];
  float* out = (float*)d_out;

  char* p = (char*)d_ws;
  auto carve = [&](size_t b) -> void* {
    void* r = (void*)p;
    p += (b + 255) & ~(size_t)255;
    return r;
  };
  // fixed buffers (~176 MB)
  __hip_bfloat16* agg = (__hip_bfloat16*)carve((size_t)NN * HS * 2);        // 80 MB
  __hip_bfloat16* h   = (__hip_bfloat16*)carve((size_t)NN * HS * 2);        // 80 MB
  __hip_bfloat16* W1T = (__hip_bfloat16*)carve((size_t)NLAYER * N1 * K1 * 2);
  __hip_bfloat16* W2T = (__hip_bfloat16*)carve((size_t)NLAYER * N2P * N1 * 2);
  float* b1p          = (float*)carve((size_t)NLAYER * N1 * 4);
  float* b2p          = (float*)carve((size_t)NLAYER * N2P * 4);
  float* etabg        = (float*)carve((size_t)NLAYER * 13 * HS * 4);        // 83 KB
  float* part         = (float*)carve((size_t)EMB * 2 * NRB * 4);           // 2.4 MB
  float* bnsc         = (float*)carve((size_t)NLAYER * HS * 4);
  float* bnsh         = (float*)carve((size_t)NLAYER * HS * 4);
  int* counts         = (int*)carve((size_t)NN * 4);
  int* indptr         = (int*)carve((size_t)(NN + 1) * 4);
  int* cursor         = (int*)carve((size_t)NN * 4);
  int* epacked        = (int*)carve((size_t)NE * 4);
  int* blockSums      = (int*)carve(128 * 4);
  int* blockOff       = (int*)carve(128 * 4);
  int* lastidx        = (int*)carve((size_t)NG * 4);

  size_t used = (size_t)(p - (char*)d_ws);
  size_t avail = (ws_size > used + 4096) ? (ws_size - used - 4096) : 0;
  int CHUNK = 16384;   // 20 MB — known-good floor
  if (avail >= (size_t)65536 * N1 * 2) CHUNK = 65536;         // 80 MB (R12 best-known)
  else if (avail >= (size_t)32768 * N1 * 2) CHUNK = 32768;    // 40 MB
  __hip_bfloat16* hid = (__hip_bfloat16*)carve((size_t)CHUNK * N1 * 2);

  hipMemsetAsync(counts, 0, (size_t)NN * 4, stream);

  prep_w1<<<(NLAYER * N1 * K1 + 255) / 256, 256, 0, stream>>>(W1, W1T);
  prep_w2<<<(NLAYER * N2P * N1 + 255) / 256, 256, 0, stream>>>(W2, W2T);
  prep_bias<<<(NLAYER * (N1 + N2P) + 255) / 256, 256, 0, stream>>>(b1, b2, b1p, b2p);
  prep_etab<<<(NLAYER * 13 * HS + 255) / 256, 256, 0, stream>>>(bond0, bond1, etabg);
  init_h<<<NN, 256, 0, stream>>>(x, atom0, atom1, h);

  count_edges<<<NE / 256, 256, 0, stream>>>(ei, counts);
  scan_block<<<128, 256, 0, stream>>>(counts, indptr, blockSums);
  scan_top<<<1, 128, 0, stream>>>(blockSums, blockOff);
  scan_add<<<128, 256, 0, stream>>>(indptr, blockOff);
  hipMemcpyAsync(cursor, indptr, (size_t)NN * 4, hipMemcpyDeviceToDevice, stream);
  scatter_edges<<<NE / 256, 256, 0, stream>>>(ei, ea, cursor, epacked);
  last_idx_kernel<<<NN / 256, 256, 0, stream>>>(batch, lastidx);

  for (int l = 0; l < NLAYER; l++) {
    if (l == 0)
      aggregate_kernel<0><<<NN / 64, 1024, 0, stream>>>(
          h, indptr, epacked, etabg + (size_t)l * 13 * HS, nullptr, nullptr, agg);
    else
      aggregate_kernel<1><<<NN / 64, 1024, 0, stream>>>(
          h, indptr, epacked, etabg + (size_t)l * 13 * HS,
          bnsc + (size_t)(l - 1) * HS, bnsh + (size_t)(l - 1) * HS, agg);
    for (int c0 = 0; c0 < NN; c0 += CHUNK) {
      gemm_kernel<1, 0, 10, K1, K1, 64><<<(CHUNK / 128) * 10, 256, 0, stream>>>(
          (const short*)(agg + (size_t)c0 * HS),
          (const short*)(W1T + (size_t)l * N1 * K1), b1p + l * N1,
          hid, nullptr, N1, N1, 0);
      gemm_kernel<0, 1, 5, N1, K2E, 64><<<(CHUNK / 128) * 5, 256, 0, stream>>>(
          (const short*)hid,
          (const short*)(W2T + (size_t)l * N2P * N1), b2p + l * N2P,
          h + (size_t)c0 * HS, part, HS, HS, c0 / 128);
    }
    bn_finalize<<<HS, 256, 0, stream>>>(part, gamma + (size_t)l * EMB, beta + (size_t)l * EMB,
                                        bnsc + (size_t)l * HS, bnsh + (size_t)l * HS);
  }

  head_kernel<<<NG, 256, 0, stream>>>(h, lastidx, bnsc + 4 * HS, bnsh + 4 * HS,
                                      hW1, hb1, hW2, hb2, out);
}

// Round 19
// 1492.387 us; speedup vs baseline: 1.2777x; 1.0604x over previous
//
#include <hip/hip_runtime.h>
#include <hip/hip_bf16.h>

#define NN 131072      // nodes
#define NE 262144      // edges (without self loops)
#define NG 4096        // graphs
#define EMB 300
#define HS 320         // h/agg row stride (bf16, padded, cols 300..319 == 0)
#define K1 320         // GEMM1 K
#define N1 640         // padded 600 (GEMM1 out / hid stride / GEMM2 K stride)
#define K2E 608        // GEMM2 K extent (cols 600..639 of hid are exact zeros)
#define N2P 384        // padded 300 (W2T rows; GEMM2 touches only rows 0..319)
#define NLAYER 5
#define NRB (NN / 128) // 1024 row-blocks for BN partials

typedef __attribute__((ext_vector_type(8))) short short8;
typedef __attribute__((ext_vector_type(4))) float f32x4;
typedef __attribute__((ext_vector_type(4))) unsigned short ushort4v;

__device__ __forceinline__ void gload_lds16(const void* g, void* l) {
  __builtin_amdgcn_global_load_lds((const __attribute__((address_space(1))) void*)g,
                                   (__attribute__((address_space(3))) void*)l, 16, 0, 0);
}
__device__ __forceinline__ float b2f(unsigned short u) {
  return __uint_as_float(((unsigned)u) << 16);
}
__device__ __forceinline__ unsigned short f2b(float x) {
  __hip_bfloat16 b = __float2bfloat16(x);
  return *(unsigned short*)&b;
}

// ---------------- prep kernels ----------------

__global__ void prep_w1(const float* __restrict__ W1, __hip_bfloat16* __restrict__ W1T) {
  int idx = blockIdx.x * 256 + threadIdx.x;           // 5*640*320
  if (idx >= NLAYER * N1 * K1) return;
  int l = idx / (N1 * K1); int r = idx % (N1 * K1);
  int n = r / K1; int k = r % K1;
  float v = (n < 600 && k < 300) ? W1[(size_t)(l * 300 + k) * 600 + n] : 0.f;
  W1T[idx] = __float2bfloat16(v);
}

__global__ void prep_w2(const float* __restrict__ W2, __hip_bfloat16* __restrict__ W2T) {
  int idx = blockIdx.x * 256 + threadIdx.x;           // 5*384*640
  if (idx >= NLAYER * N2P * N1) return;
  int l = idx / (N2P * N1); int r = idx % (N2P * N1);
  int n = r / N1; int k = r % N1;
  float v = (n < 300 && k < 600) ? W2[(size_t)(l * 600 + k) * 300 + n] : 0.f;
  W2T[idx] = __float2bfloat16(v);
}

__global__ void prep_bias(const float* __restrict__ b1, const float* __restrict__ b2,
                          float* __restrict__ b1p, float* __restrict__ b2p) {
  int idx = blockIdx.x * 256 + threadIdx.x;
  if (idx < NLAYER * N1) {
    int l = idx / N1, n = idx % N1;
    b1p[idx] = (n < 600) ? b1[l * 600 + n] : 0.f;
  } else {
    int k = idx - NLAYER * N1;
    if (k < NLAYER * N2P) {
      int l = k / N2P, n = k % N2P;
      b2p[k] = (n < 300) ? b2[l * 300 + n] : 0.f;
    }
  }
}

// edge-embedding tables for ALL layers: etabg[l][c][ch], c=0..12 (12 combos + self)
__global__ void prep_etab(const float* __restrict__ bond0, const float* __restrict__ bond1,
                          float* __restrict__ etabg) {
  int idx = blockIdx.x * 256 + threadIdx.x;
  if (idx >= NLAYER * 13 * HS) return;
  int l = idx / (13 * HS); int r = idx % (13 * HS);
  int c = r / HS; int ch = r % HS;
  float val = 0.f;
  if (ch < EMB) {
    int t0 = (c < 12) ? (c / 3) : 4;     // self-loop: bond type 4, dir 0
    int t1 = (c < 12) ? (c % 3) : 0;
    val = bond0[(size_t)(l * 6 + t0) * EMB + ch] + bond1[(size_t)(l * 3 + t1) * EMB + ch];
  }
  etabg[idx] = val;
}

__global__ void init_h(const int* __restrict__ x, const float* __restrict__ ae0,
                       const float* __restrict__ ae1, __hip_bfloat16* __restrict__ h) {
  int v = blockIdx.x; int t = threadIdx.x;
  int x0 = x[2 * v], x1 = x[2 * v + 1];
  for (int c = t; c < HS; c += 256)
    h[(size_t)v * HS + c] = __float2bfloat16(c < EMB ? ae0[x0 * EMB + c] + ae1[x1 * EMB + c] : 0.f);
}

// ---------------- CSR build ----------------

__global__ void count_edges(const int* __restrict__ ei, int* __restrict__ counts) {
  int j = blockIdx.x * 256 + threadIdx.x;
  if (j >= NE) return;
  atomicAdd(&counts[ei[NE + j]], 1);
}

__global__ void scan_block(const int* __restrict__ counts, int* __restrict__ indptr,
                           int* __restrict__ blockSums) {
  __shared__ int s[256];
  int b = blockIdx.x, t = threadIdx.x;
  int base = b * 1024 + t * 4;
  int4 c = *(const int4*)&counts[base];
  int tsum = c.x + c.y + c.z + c.w;
  s[t] = tsum;
  __syncthreads();
  for (int off = 1; off < 256; off <<= 1) {
    int v = (t >= off) ? s[t - off] : 0;
    __syncthreads();
    s[t] += v;
    __syncthreads();
  }
  int excl = (t == 0) ? 0 : s[t - 1];
  indptr[base + 0] = excl;
  indptr[base + 1] = excl + c.x;
  indptr[base + 2] = excl + c.x + c.y;
  indptr[base + 3] = excl + c.x + c.y + c.z;
  if (t == 255) blockSums[b] = s[255];
}

__global__ void scan_top(const int* __restrict__ blockSums, int* __restrict__ blockOff) {
  __shared__ int s[128];
  int t = threadIdx.x;
  s[t] = blockSums[t];
  __syncthreads();
  for (int off = 1; off < 128; off <<= 1) {
    int v = (t >= off) ? s[t - off] : 0;
    __syncthreads();
    s[t] += v;
    __syncthreads();
  }
  blockOff[t] = (t == 0) ? 0 : s[t - 1];
}

__global__ void scan_add(int* __restrict__ indptr, const int* __restrict__ blockOff) {
  int b = blockIdx.x, t = threadIdx.x;
  int off = blockOff[b];
  int base = b * 1024 + t * 4;
  indptr[base + 0] += off; indptr[base + 1] += off;
  indptr[base + 2] += off; indptr[base + 3] += off;
  if (b == 127 && t == 255) indptr[NN] = NE;
}

__global__ void scatter_edges(const int* __restrict__ ei, const int* __restrict__ ea,
                              int* __restrict__ cursor, int* __restrict__ epacked) {
  int j = blockIdx.x * 256 + threadIdx.x;
  if (j >= NE) return;
  int dst = ei[NE + j];
  int src = ei[j];
  int c = ea[2 * j] * 3 + ea[2 * j + 1];   // 0..11
  int pos = atomicAdd(&cursor[dst], 1);
  epacked[pos] = src | (c << 17);
}

__global__ void last_idx_kernel(const int* __restrict__ batch, int* __restrict__ lastidx) {
  int i = blockIdx.x * 256 + threadIdx.x;
  if (i >= NN) return;
  int b = batch[i];
  if (i == NN - 1 || batch[i + 1] != b) lastidx[b] = i;
}

// ---------------- aggregate (fused BN-apply + ReLU of previous layer) ----------------
// etab copied from precomputed global table; 64 nodes/block (4 per wave);
// 2-wide edge unroll (28 VGPR — R7's 4-wide cost occupancy).
template<int BN>
__global__ __launch_bounds__(1024)
void aggregate_kernel(const __hip_bfloat16* __restrict__ hg, const int* __restrict__ indptr,
                      const int* __restrict__ epacked, const float* __restrict__ etabg,
                      const float* __restrict__ bnsc, const float* __restrict__ bnsh,
                      __hip_bfloat16* __restrict__ agg) {
  __shared__ float etab[13 * HS];
  const int tid = threadIdx.x;
#pragma unroll
  for (int idx = tid; idx < 13 * HS; idx += 1024)
    etab[idx] = etabg[idx];
  __syncthreads();
  const int wid = tid >> 6, lane = tid & 63;
  const int cA = lane * 4, cB = 256 + lane;
  const unsigned short* h = (const unsigned short*)hg;

  f32x4 scA = {1.f, 1.f, 1.f, 1.f}, shA = {0.f, 0.f, 0.f, 0.f};
  float scB = 1.f, shB = 0.f;
  if (BN) {
    scA = *(const f32x4*)&bnsc[cA]; shA = *(const f32x4*)&bnsh[cA];
    scB = bnsc[cB]; shB = bnsh[cB];
  }
  auto trA = [&](float x, int k) -> float {
    if (BN) x = fmaxf(fmaf(x, scA[k], shA[k]), 0.f);
    return x;
  };
  auto trB = [&](float x) -> float {
    if (BN) x = fmaxf(fmaf(x, scB, shB), 0.f);
    return x;
  };
  const float* es = etab + 12 * HS;

  for (int it = 0; it < 4; ++it) {
    const int v = blockIdx.x * 64 + it * 16 + wid;
    const unsigned short* hv = h + (size_t)v * HS;
    ushort4v pA = *(const ushort4v*)(hv + cA);
    unsigned short pB = hv[cB];
    float a0 = trA(b2f(pA[0]), 0) + es[cA];
    float a1 = trA(b2f(pA[1]), 1) + es[cA + 1];
    float a2 = trA(b2f(pA[2]), 2) + es[cA + 2];
    float a3 = trA(b2f(pA[3]), 3) + es[cA + 3];
    float a4 = trB(b2f(pB)) + es[cB];

    const int jb = indptr[v], je = indptr[v + 1];
    int j = jb;
    for (; j + 2 <= je; j += 2) {
      int p0 = epacked[j], p1 = epacked[j + 1];
      const unsigned short* h0 = h + (size_t)(p0 & (NN - 1)) * HS;
      const unsigned short* h1 = h + (size_t)(p1 & (NN - 1)) * HS;
      ushort4v q0 = *(const ushort4v*)(h0 + cA);
      ushort4v q1 = *(const ushort4v*)(h1 + cA);
      unsigned short r0 = h0[cB], r1 = h1[cB];
      const float* e0 = etab + (p0 >> 17) * HS;
      const float* e1 = etab + (p1 >> 17) * HS;
      a0 += trA(b2f(q0[0]), 0) + e0[cA]     + trA(b2f(q1[0]), 0) + e1[cA];
      a1 += trA(b2f(q0[1]), 1) + e0[cA + 1] + trA(b2f(q1[1]), 1) + e1[cA + 1];
      a2 += trA(b2f(q0[2]), 2) + e0[cA + 2] + trA(b2f(q1[2]), 2) + e1[cA + 2];
      a3 += trA(b2f(q0[3]), 3) + e0[cA + 3] + trA(b2f(q1[3]), 3) + e1[cA + 3];
      a4 += trB(b2f(r0)) + e0[cB] + trB(b2f(r1)) + e1[cB];
    }
    if (j < je) {
      int p0 = epacked[j];
      const unsigned short* h0 = h + (size_t)(p0 & (NN - 1)) * HS;
      ushort4v q0 = *(const ushort4v*)(h0 + cA);
      unsigned short r0 = h0[cB];
      const float* e0 = etab + (p0 >> 17) * HS;
      a0 += trA(b2f(q0[0]), 0) + e0[cA];
      a1 += trA(b2f(q0[1]), 1) + e0[cA + 1];
      a2 += trA(b2f(q0[2]), 2) + e0[cA + 2];
      a3 += trA(b2f(q0[3]), 3) + e0[cA + 3];
      a4 += trB(b2f(r0)) + e0[cB];
    }

    unsigned short* av = (unsigned short*)agg + (size_t)v * HS;
    ushort4v o; o[0] = f2b(a0); o[1] = f2b(a1); o[2] = f2b(a2); o[3] = f2b(a3);
    *(ushort4v*)(av + cA) = o;
    av[cB] = f2b(a4);
  }
}

// ---------------- GEMM ----------------
// 128-row tiles; NWAVES waves, wave grid 2 x (NWAVES/2), each wave 64 x WCOL.
// GEMM1: NWAVES=8, BCOLS=128 (16 KB/buf, 48 KB -> 3 blocks/CU = 24 waves/CU,
//        2 gloads/stage, vmcnt(2)).   [R19: more waves at same per-wave work]
// GEMM2: NWAVES=4, BCOLS=64  (12 KB/buf, 36 KB -> 4 blocks/CU = 16 waves/CU,
//        3 gloads/stage, vmcnt(3)).   [R18 winner, unchanged]
// 3-buffer LDS, ONE barrier per K-step, 2-step prefetch, compile-time K,
// XOR-swizzled k-slots (dest linear per rule #21), XCD-bijective remap.
template<int RELU, int STATS, int NBN, int KSTRIDE, int KEXT, int BCOLS, int NWAVES>
__global__ __launch_bounds__(NWAVES * 64)
void gemm_kernel(const short* __restrict__ A, const short* __restrict__ BT,
                 const float* __restrict__ bias, __hip_bfloat16* __restrict__ Cout,
                 float* __restrict__ part, int outStride, int outBound, int rbBase) {
  constexpr int THREADS = NWAVES * 64;
  constexpr int BSH = BCOLS * 32;          // B shorts per buffer
  constexpr int BUFSZ = 4096 + BSH;        // shorts per buffer (A 128x32 + B)
  constexpr int NCW = NWAVES / 2;          // col-waves
  constexpr int WCOL = BCOLS / NCW;        // cols per wave
  constexpr int NF = WCOL / 16;            // col fragments per wave
  __shared__ short smem[3 * BUFSZ];
  __shared__ float sred[STATS ? BCOLS : 1][2];
  const int tid = threadIdx.x;
  const int wid = tid >> 6, lane = tid & 63;
  const int wm = wid / NCW, wn = wid % NCW;
  f32x4 acc[4][NF] = {};

  // XCD-bijective remap (gridDim.x % 8 == 0 in all launch configs)
  const int cpx = gridDim.x >> 3;
  const int logical = (blockIdx.x & 7) * cpx + (blockIdx.x >> 3);
  const int bn = logical % NBN;
  const int bm = logical / NBN;

  const short* Ag = A + (size_t)bm * 128 * KSTRIDE;
  const short* Bg = BT + (size_t)bn * BCOLS * KSTRIDE;
  const int r2 = tid >> 2;                                   // staged row
  const int ksw = ((tid & 3) ^ ((tid >> 3) & 3)) * 8;        // swizzled k-src (shorts)
  const int arow_h = lane & 15;                              // read row within 16
  const int koffR = (((lane >> 4) ^ ((arow_h >> 1) & 3)) * 8);  // swizzled k-read (shorts)

  const short* Ao = Ag + (size_t)r2 * KSTRIDE + ksw;
  const short* Bo = Bg + (size_t)r2 * KSTRIDE + ksw;

  auto stage = [&](int buf, int kt) {
    short* s = smem + buf * BUFSZ;
    gload_lds16(Ao + kt, s + tid * 8);
    if constexpr (THREADS == 256)                     // 256 thr: rows 0..63 done, add 64..127
      gload_lds16(Ao + kt + 64 * KSTRIDE, s + 2048 + tid * 8);
    gload_lds16(Bo + kt, s + 4096 + tid * 8);         // B rows 0..BCOLS-1 in one pass
  };

  constexpr int NT = KEXT / 32;
  stage(0, 0);
  stage(1, 32);
#pragma unroll
  for (int t = 0; t < NT; ++t) {
    if (t + 1 < NT) {
      if constexpr (THREADS == 256) asm volatile("s_waitcnt vmcnt(3)" ::: "memory");
      else                          asm volatile("s_waitcnt vmcnt(2)" ::: "memory");
    } else {
      asm volatile("s_waitcnt vmcnt(0)" ::: "memory");
    }
    __builtin_amdgcn_sched_barrier(0);
    __builtin_amdgcn_s_barrier();
    const int rb = t % 3;
    if (t + 2 < NT) stage((t + 2) % 3, (t + 2) * 32);
    const short* sA = smem + rb * BUFSZ + wm * 2048;
    const short* sB = smem + rb * BUFSZ + 4096 + wn * (WCOL * 32);
    short8 af[4], bf[NF];
#pragma unroll
    for (int i = 0; i < 4; i++) af[i] = *(const short8*)&sA[(arow_h + i * 16) * 32 + koffR];
#pragma unroll
    for (int j = 0; j < NF; j++) bf[j] = *(const short8*)&sB[(arow_h + j * 16) * 32 + koffR];
#pragma unroll
    for (int i = 0; i < 4; i++)
#pragma unroll
      for (int j = 0; j < NF; j++)
        acc[i][j] = __builtin_amdgcn_mfma_f32_16x16x32_bf16(af[i], bf[j], acc[i][j], 0, 0, 0);
    __builtin_amdgcn_sched_barrier(0);
  }

  const int row0 = bm * 128 + wm * 64 + (lane >> 4) * 4;
  const int col0 = bn * BCOLS + wn * WCOL + (lane & 15);
  float bs[NF];
#pragma unroll
  for (int j = 0; j < NF; j++) bs[j] = bias[col0 + j * 16];
  float ssum[NF], ssq[NF];
#pragma unroll
  for (int j = 0; j < NF; j++) { ssum[j] = 0.f; ssq[j] = 0.f; }
  if (STATS) {
    if (tid < BCOLS) { sred[tid][0] = 0.f; sred[tid][1] = 0.f; }
    __syncthreads();
  }
#pragma unroll
  for (int i = 0; i < 4; i++) {
#pragma unroll
    for (int p = 0; p < 4; p++) {
      const size_t row = row0 + i * 16 + p;
#pragma unroll
      for (int j = 0; j < NF; j++) {
        const int col = col0 + j * 16;
        float v = acc[i][j][p] + bs[j];
        if (STATS) { ssum[j] += v; ssq[j] += v * v; }
        if (RELU) v = fmaxf(v, 0.f);
        if (col < outBound)
          Cout[row * (size_t)outStride + col] = __float2bfloat16(v);
      }
    }
  }
  if (STATS) {
#pragma unroll
    for (int j = 0; j < NF; j++) {
      const int cw = wn * WCOL + j * 16 + (lane & 15);
      atomicAdd(&sred[cw][0], ssum[j]);
      atomicAdd(&sred[cw][1], ssq[j]);
    }
    __syncthreads();
    if (tid < BCOLS) {
      const int col = bn * BCOLS + tid;
      if (col < EMB) {
        const int rb2 = rbBase + bm;
        part[(size_t)col * (2 * NRB) + rb2] = sred[tid][0];
        part[(size_t)col * (2 * NRB) + NRB + rb2] = sred[tid][1];
      }
    }
  }
}

// ---------------- BN finalize: partials -> scale/shift ----------------
__global__ __launch_bounds__(256)
void bn_finalize(const float* __restrict__ part, const float* __restrict__ gamma,
                 const float* __restrict__ beta, float* __restrict__ bnsc,
                 float* __restrict__ bnsh) {
  __shared__ float rs[256], rq[256];
  const int c = blockIdx.x, t = threadIdx.x;
  if (c >= EMB) {
    if (t == 0) { bnsc[c] = 0.f; bnsh[c] = 0.f; }
    return;
  }
  float s = 0.f, q = 0.f;
  for (int rb = t; rb < NRB; rb += 256) {
    s += part[(size_t)c * (2 * NRB) + rb];
    q += part[(size_t)c * (2 * NRB) + NRB + rb];
  }
  rs[t] = s; rq[t] = q;
  __syncthreads();
  for (int off = 128; off > 0; off >>= 1) {
    if (t < off) { rs[t] += rs[t + off]; rq[t] += rq[t + off]; }
    __syncthreads();
  }
  if (t == 0) {
    float mean = rs[0] / (float)NN;
    float var = rq[0] / (float)NN - mean * mean;
    float sc = rsqrtf(var + 1e-5f) * gamma[c];
    bnsc[c] = sc;
    bnsh[c] = beta[c] - mean * sc;
  }
}

// ---------------- head (applies final BN, no relu) ----------------
__global__ __launch_bounds__(256)
void head_kernel(const __hip_bfloat16* __restrict__ h, const int* __restrict__ lastidx,
                 const float* __restrict__ bnsc4, const float* __restrict__ bnsh4,
                 const float* __restrict__ hW1, const float* __restrict__ hb1,
                 const float* __restrict__ hW2, const float* __restrict__ hb2,
                 float* __restrict__ out) {
  __shared__ float sup[EMB];
  __shared__ float red[256];
  int g = blockIdx.x, t = threadIdx.x;
  int v = lastidx[g];
  for (int c = t; c < EMB; c += 256)
    sup[c] = b2f(((const unsigned short*)h)[(size_t)v * HS + c]) * bnsc4[c] + bnsh4[c];
  __syncthreads();
  float val = 0.f;
  if (t < 150) {
    float acc = hb1[t];
    for (int k = 0; k < EMB; k++) acc += sup[k] * hW1[k * 150 + t];
    float e = (acc > 0.f) ? acc : (expf(acc) - 1.f);   // elu
    val = e * hW2[t];
  }
  red[t] = val;
  __syncthreads();
  for (int off = 128; off > 0; off >>= 1) {
    if (t < off) red[t] += red[t + off];
    __syncthreads();
  }
  if (t == 0) out[g] = red[0] + hb2[0];
}

// ---------------- host ----------------

extern "C" void kernel_launch(void* const* d_in, const int* in_sizes, int n_in,
                              void* d_out, int out_size, void* d_ws, size_t ws_size,
                              hipStream_t stream) {
  const int* x      = (const int*)d_in[0];
  const int* ei     = (const int*)d_in[1];
  const int* ea     = (const int*)d_in[2];
  const int* batch  = (const int*)d_in[3];
  // d_in[4] = num_graphs (static)
  const float* atom0 = (const float*)d_in[5];
  const float* atom1 = (const float*)d_in[6];
  const float* bond0 = (const float*)d_in[7];
  const float* bond1 = (const float*)d_in[8];
  const float* W1    = (const float*)d_in[9];
  const float* b1    = (const float*)d_in[10];
  const float* W2    = (const float*)d_in[11];
  const float* b2    = (const float*)d_in[12];
  const float* gamma = (const float*)d_in[13];
  const float* beta  = (const float*)d_in[14];
  const float* hW1   = (const float*)d_in[15];
  const float* hb1   = (const float*)d_in[16];
  const float* hW2   = (const float*)d_in[17];
  const float* hb2   = (const float*)d_in[18];
  float* out = (float*)d_out;

  char* p = (char*)d_ws;
  auto carve = [&](size_t b) -> void* {
    void* r = (void*)p;
    p += (b + 255) & ~(size_t)255;
    return r;
  };
  // fixed buffers (~176 MB)
  __hip_bfloat16* agg = (__hip_bfloat16*)carve((size_t)NN * HS * 2);        // 80 MB
  __hip_bfloat16* h   = (__hip_bfloat16*)carve((size_t)NN * HS * 2);        // 80 MB
  __hip_bfloat16* W1T = (__hip_bfloat16*)carve((size_t)NLAYER * N1 * K1 * 2);
  __hip_bfloat16* W2T = (__hip_bfloat16*)carve((size_t)NLAYER * N2P * N1 * 2);
  float* b1p          = (float*)carve((size_t)NLAYER * N1 * 4);
  float* b2p          = (float*)carve((size_t)NLAYER * N2P * 4);
  float* etabg        = (float*)carve((size_t)NLAYER * 13 * HS * 4);        // 83 KB
  float* part         = (float*)carve((size_t)EMB * 2 * NRB * 4);           // 2.4 MB
  float* bnsc         = (float*)carve((size_t)NLAYER * HS * 4);
  float* bnsh         = (float*)carve((size_t)NLAYER * HS * 4);
  int* counts         = (int*)carve((size_t)NN * 4);
  int* indptr         = (int*)carve((size_t)(NN + 1) * 4);
  int* cursor         = (int*)carve((size_t)NN * 4);
  int* epacked        = (int*)carve((size_t)NE * 4);
  int* blockSums      = (int*)carve(128 * 4);
  int* blockOff       = (int*)carve(128 * 4);
  int* lastidx        = (int*)carve((size_t)NG * 4);

  size_t used = (size_t)(p - (char*)d_ws);
  size_t avail = (ws_size > used + 4096) ? (ws_size - used - 4096) : 0;
  int CHUNK = 16384;   // 20 MB — known-good floor
  if (avail >= (size_t)65536 * N1 * 2) CHUNK = 65536;         // 80 MB (best-known)
  else if (avail >= (size_t)32768 * N1 * 2) CHUNK = 32768;    // 40 MB
  __hip_bfloat16* hid = (__hip_bfloat16*)carve((size_t)CHUNK * N1 * 2);

  hipMemsetAsync(counts, 0, (size_t)NN * 4, stream);

  prep_w1<<<(NLAYER * N1 * K1 + 255) / 256, 256, 0, stream>>>(W1, W1T);
  prep_w2<<<(NLAYER * N2P * N1 + 255) / 256, 256, 0, stream>>>(W2, W2T);
  prep_bias<<<(NLAYER * (N1 + N2P) + 255) / 256, 256, 0, stream>>>(b1, b2, b1p, b2p);
  prep_etab<<<(NLAYER * 13 * HS + 255) / 256, 256, 0, stream>>>(bond0, bond1, etabg);
  init_h<<<NN, 256, 0, stream>>>(x, atom0, atom1, h);

  count_edges<<<NE / 256, 256, 0, stream>>>(ei, counts);
  scan_block<<<128, 256, 0, stream>>>(counts, indptr, blockSums);
  scan_top<<<1, 128, 0, stream>>>(blockSums, blockOff);
  scan_add<<<128, 256, 0, stream>>>(indptr, blockOff);
  hipMemcpyAsync(cursor, indptr, (size_t)NN * 4, hipMemcpyDeviceToDevice, stream);
  scatter_edges<<<NE / 256, 256, 0, stream>>>(ei, ea, cursor, epacked);
  last_idx_kernel<<<NN / 256, 256, 0, stream>>>(batch, lastidx);

  for (int l = 0; l < NLAYER; l++) {
    if (l == 0)
      aggregate_kernel<0><<<NN / 64, 1024, 0, stream>>>(
          h, indptr, epacked, etabg + (size_t)l * 13 * HS, nullptr, nullptr, agg);
    else
      aggregate_kernel<1><<<NN / 64, 1024, 0, stream>>>(
          h, indptr, epacked, etabg + (size_t)l * 13 * HS,
          bnsc + (size_t)(l - 1) * HS, bnsh + (size_t)(l - 1) * HS, agg);
    for (int c0 = 0; c0 < NN; c0 += CHUNK) {
      gemm_kernel<1, 0, 5, K1, K1, 128, 8><<<(CHUNK / 128) * 5, 512, 0, stream>>>(
          (const short*)(agg + (size_t)c0 * HS),
          (const short*)(W1T + (size_t)l * N1 * K1), b1p + l * N1,
          hid, nullptr, N1, N1, 0);
      gemm_kernel<0, 1, 5, N1, K2E, 64, 4><<<(CHUNK / 128) * 5, 256, 0, stream>>>(
          (const short*)hid,
          (const short*)(W2T + (size_t)l * N2P * N1), b2p + l * N2P,
          h + (size_t)c0 * HS, part, HS, HS, c0 / 128);
    }
    bn_finalize<<<HS, 256, 0, stream>>>(part, gamma + (size_t)l * EMB, beta + (size_t)l * EMB,
                                        bnsc + (size_t)l * HS, bnsh + (size_t)l * HS);
  }

  head_kernel<<<NG, 256, 0, stream>>>(h, lastidx, bnsc + 4 * HS, bnsh + 4 * HS,
                                      hW1, hb1, hW2, hb2, out);
}